// Round 2
// baseline (8232.449 us; speedup 1.0000x reference)
//
#include <hip/hip_runtime.h>
#include <math.h>

// ---------------- utility kernels ----------------

__global__ __launch_bounds__(256) void zero_f32(float* __restrict__ p, int n) {
  int i = blockIdx.x * 256 + threadIdx.x;
  if (i < n) p[i] = 0.f;
}

__global__ __launch_bounds__(256) void deg_accum(const int* __restrict__ dst,
                                                 const float* __restrict__ ew,
                                                 float* __restrict__ deg, int E) {
  int i = blockIdx.x * 256 + threadIdx.x;
  if (i < E) atomicAdd(&deg[dst[i]], ew[i]);
}

__global__ __launch_bounds__(256) void deg_to_dinv(float* __restrict__ d, int n) {
  int i = blockIdx.x * 256 + threadIdx.x;
  if (i < n) d[i] = rsqrtf(d[i] + 2.0f);  // + self-loop weight 2.0; deg >= 2 always
}

// ---------------- self-loop init: out[n][:] = in[n][:] * 2*dinv[n]^2 ----------------

template <int F>
__global__ __launch_bounds__(256) void selfloop(const float* __restrict__ in,
                                                const float* __restrict__ dinv,
                                                float* __restrict__ out, int N) {
  int i = blockIdx.x * 256 + threadIdx.x;  // float4 index
  int total = N * (F / 4);
  if (i >= total) return;
  int n = i / (F / 4);
  float dv = dinv[n];
  float s = 2.f * dv * dv;
  float4 v = *(const float4*)&in[(long)i * 4];
  v.x *= s; v.y *= s; v.z *= s; v.w *= s;
  *(float4*)&out[(long)i * 4] = v;
}

// ---------------- edge scatter (full width F): out[dst] += in[src]*cf ----------------

template <int F>
__global__ __launch_bounds__(256) void scatter(const float* __restrict__ in,
                                               const int* __restrict__ src,
                                               const int* __restrict__ dst,
                                               const float* __restrict__ ew,
                                               const float* __restrict__ dinv,
                                               float* __restrict__ out, int E) {
  constexpr int TPE = F / 4;
  constexpr int EPB = 256 / TPE;
  const int lane = threadIdx.x % TPE;
  const long e = (long)blockIdx.x * EPB + threadIdx.x / TPE;
  if (e >= E) return;
  const int s = src[e], d = dst[e];
  const float cf = dinv[s] * ew[e] * dinv[d];
  const float4 hv = *(const float4*)&in[(long)s * F + lane * 4];
  float* o = &out[(long)d * F + lane * 4];
  atomicAdd(o + 0, hv.x * cf);
  atomicAdd(o + 1, hv.y * cf);
  atomicAdd(o + 2, hv.z * cf);
  atomicAdd(o + 3, hv.w * cf);
}

// ---------------- in-place GEMM: A[N][128] = A[N][128] @ W[128][128] ----------------
// Each block owns rows [64b, 64b+64): stages them to LDS once, then overwrites only
// those rows. ct (column-half) loop is INSIDE the block so no cross-block A read/write
// race exists (a 2D ct-grid would race: (b,1) reads cols 0:128 while (b,0) writes 0:64).

__global__ __launch_bounds__(256) void gemm_inplace128(float* __restrict__ A,
                                                       const float* __restrict__ W,
                                                       int N) {
  __shared__ float Al[64][128];  // 32 KiB
  __shared__ float Wl[128][64];  // 32 KiB
  const int row0 = blockIdx.x * 64;
  for (int i = threadIdx.x * 4; i < 64 * 128; i += 1024) {
    int r = i >> 7, k = i & 127;
    float4 v = make_float4(0.f, 0.f, 0.f, 0.f);
    if (row0 + r < N) v = *(const float4*)&A[(long)(row0 + r) * 128 + k];
    *(float4*)&Al[r][k] = v;
  }
  __syncthreads();
  const int cg = threadIdx.x & 15;
  const int rg = threadIdx.x >> 4;
  const int c = cg * 4, r0 = rg * 4;
  for (int ct = 0; ct < 2; ++ct) {
    for (int i = threadIdx.x * 4; i < 128 * 64; i += 1024) {
      int k = i >> 6, cc = i & 63;
      *(float4*)&Wl[k][cc] = *(const float4*)&W[(long)k * 128 + ct * 64 + cc];
    }
    __syncthreads();
    float acc[4][4] = {};
#pragma unroll 4
    for (int k = 0; k < 128; ++k) {
      const float4 w = *(const float4*)&Wl[k][c];
#pragma unroll
      for (int i = 0; i < 4; ++i) {
        const float a = Al[r0 + i][k];
        acc[i][0] = fmaf(a, w.x, acc[i][0]);
        acc[i][1] = fmaf(a, w.y, acc[i][1]);
        acc[i][2] = fmaf(a, w.z, acc[i][2]);
        acc[i][3] = fmaf(a, w.w, acc[i][3]);
      }
    }
#pragma unroll
    for (int i = 0; i < 4; ++i) {
      int r = row0 + r0 + i;
      if (r < N)
        *(float4*)&A[(long)r * 128 + ct * 64 + c] =
            make_float4(acc[i][0], acc[i][1], acc[i][2], acc[i][3]);
    }
    __syncthreads();  // protect Wl before next ct restage
  }
}

// ---------------- layer-2 tile GEMM: r2[N][16] = relu(A+b0) @ W1[:, c0:c0+16] ----------------

__global__ __launch_bounds__(256) void gemm_tile16(const float* __restrict__ A,
                                                   const float* __restrict__ bias,
                                                   const float* __restrict__ W,
                                                   int c0, float* __restrict__ r2,
                                                   int N) {
  __shared__ float Al[64][132];  // +4 pad: Al[r][k] bank = (4r+k)%32 -> <=2-way
  __shared__ float Wl[128][16];
  const int row0 = blockIdx.x * 64;
  for (int i = threadIdx.x * 4; i < 64 * 128; i += 1024) {
    int r = i >> 7, k = i & 127;
    float4 v = make_float4(0.f, 0.f, 0.f, 0.f);
    if (row0 + r < N) {
      v = *(const float4*)&A[(long)(row0 + r) * 128 + k];
      const float4 b = *(const float4*)&bias[k];
      v.x = fmaxf(v.x + b.x, 0.f);
      v.y = fmaxf(v.y + b.y, 0.f);
      v.z = fmaxf(v.z + b.z, 0.f);
      v.w = fmaxf(v.w + b.w, 0.f);
    }
    *(float4*)&Al[r][k] = v;  // pad stride 132: offset 132r+k stays 16B-aligned (k%4==0)
  }
  for (int i = threadIdx.x * 4; i < 128 * 16; i += 1024) {
    int k = i >> 4, cc = i & 15;
    *(float4*)&Wl[k][cc] = *(const float4*)&W[(long)k * 64 + c0 + cc];
  }
  __syncthreads();
  const int rg = threadIdx.x >> 2;         // 64 rows, 1 row/thread
  const int c = (threadIdx.x & 3) * 4;     // 16 cols, 4 cols/thread
  float acc[4] = {0.f, 0.f, 0.f, 0.f};
#pragma unroll 4
  for (int k = 0; k < 128; ++k) {
    const float4 w = *(const float4*)&Wl[k][c];
    const float a = Al[rg][k];
    acc[0] = fmaf(a, w.x, acc[0]);
    acc[1] = fmaf(a, w.y, acc[1]);
    acc[2] = fmaf(a, w.z, acc[2]);
    acc[3] = fmaf(a, w.w, acc[3]);
  }
  if (row0 + rg < N)
    *(float4*)&r2[(long)(row0 + rg) * 16 + c] =
        make_float4(acc[0], acc[1], acc[2], acc[3]);
}

// ---------------- layer-2 tile selfloop / scatter into out[:, c0:c0+16] ----------------

__global__ __launch_bounds__(256) void selfloop_t16(const float* __restrict__ r2,
                                                    const float* __restrict__ dinv,
                                                    float* __restrict__ out, int c0,
                                                    int N) {
  int i = blockIdx.x * 256 + threadIdx.x;  // float4 index over N*4
  if (i >= N * 4) return;
  int n = i >> 2;
  int c = (i & 3) * 4;
  float dv = dinv[n];
  float s = 2.f * dv * dv;
  float4 v = *(const float4*)&r2[(long)n * 16 + c];
  v.x *= s; v.y *= s; v.z *= s; v.w *= s;
  *(float4*)&out[(long)n * 64 + c0 + c] = v;
}

__global__ __launch_bounds__(256) void scatter_t16(const float* __restrict__ r2,
                                                   const int* __restrict__ src,
                                                   const int* __restrict__ dst,
                                                   const float* __restrict__ ew,
                                                   const float* __restrict__ dinv,
                                                   float* __restrict__ out, int c0,
                                                   int E) {
  const int lane = threadIdx.x & 3;                       // 4 threads/edge
  const long e = (long)blockIdx.x * 64 + (threadIdx.x >> 2);
  if (e >= E) return;
  const int s = src[e], d = dst[e];
  const float cf = dinv[s] * ew[e] * dinv[d];
  const float4 hv = *(const float4*)&r2[(long)s * 16 + lane * 4];
  float* o = &out[(long)d * 64 + c0 + lane * 4];
  atomicAdd(o + 0, hv.x * cf);
  atomicAdd(o + 1, hv.y * cf);
  atomicAdd(o + 2, hv.z * cf);
  atomicAdd(o + 3, hv.w * cf);
}

// ---------------- final: out = sigmoid(out + b1) ----------------

__global__ __launch_bounds__(256) void bias_sigmoid(float* __restrict__ io,
                                                    const float* __restrict__ bias,
                                                    int N) {
  int i = blockIdx.x * 256 + threadIdx.x;  // float4 index over N*16
  if (i >= N * 16) return;
  int c4 = (i & 15) * 4;
  float4 v = *(float4*)&io[(long)i * 4];
  const float4 b = *(const float4*)&bias[c4];
  v.x = 1.f / (1.f + __expf(-(v.x + b.x)));
  v.y = 1.f / (1.f + __expf(-(v.y + b.y)));
  v.z = 1.f / (1.f + __expf(-(v.z + b.z)));
  v.w = 1.f / (1.f + __expf(-(v.w + b.w)));
  *(float4*)&io[(long)i * 4] = v;
}

// ---------------- launch ----------------
// Math: out = sigmoid( A2 @ W1 + b1 ) with A2 = Ahat @ relu(Ahat @ x @ W0 + b0),
// using Ahat(x W0) == (Ahat x) W0 (GCN linearity) to aggregate layer 1 FIRST,
// enabling in-place GEMM and a ~58 MB workspace footprint (was ~103 MB -> overflow).

extern "C" void kernel_launch(void* const* d_in, const int* in_sizes, int n_in,
                              void* d_out, int out_size, void* d_ws, size_t ws_size,
                              hipStream_t stream) {
  const float* x  = (const float*)d_in[0];
  const int* src  = (const int*)d_in[1];
  const float* ew = (const float*)d_in[2];
  const float* W0 = (const float*)d_in[3];
  const float* b0 = (const float*)d_in[4];
  const float* W1 = (const float*)d_in[5];
  const float* b1 = (const float*)d_in[6];
  float* out = (float*)d_out;

  const int N = in_sizes[0] / 128;
  const int E = in_sizes[2];
  const int* dstp = src + E;

  // workspace (floats): dinv [oN] | buf1 [N*128] (xa -> h1 in place) | r2 [N*16]
  float* ws = (float*)d_ws;
  const size_t oN = ((size_t)N + 255) & ~(size_t)255;
  float* dinv = ws;
  float* buf1 = ws + oN;
  float* r2   = buf1 + (size_t)N * 128;

  int nb;
  // degree -> dinv
  nb = (N + 255) / 256;
  zero_f32<<<nb, 256, 0, stream>>>(dinv, N);
  nb = (E + 255) / 256;
  deg_accum<<<nb, 256, 0, stream>>>(dstp, ew, dinv, E);
  nb = (N + 255) / 256;
  deg_to_dinv<<<nb, 256, 0, stream>>>(dinv, N);

  // layer 1, aggregate-first: xa = Ahat @ x (into buf1)
  nb = (N * 32 + 255) / 256;
  selfloop<128><<<nb, 256, 0, stream>>>(x, dinv, buf1, N);
  nb = (E + 7) / 8;
  scatter<128><<<nb, 256, 0, stream>>>(x, src, dstp, ew, dinv, buf1, E);

  // h1 = xa @ W0 (in place; bias b0 fused into layer-2 A-stage)
  nb = (N + 63) / 64;
  gemm_inplace128<<<nb, 256, 0, stream>>>(buf1, W0, N);

  // layer 2 in four 16-column tiles
  for (int t = 0; t < 4; ++t) {
    const int c0 = t * 16;
    nb = (N + 63) / 64;
    gemm_tile16<<<nb, 256, 0, stream>>>(buf1, b0, W1, c0, r2, N);
    nb = (N * 4 + 255) / 256;
    selfloop_t16<<<nb, 256, 0, stream>>>(r2, dinv, out, c0, N);
    nb = (E + 63) / 64;
    scatter_t16<<<nb, 256, 0, stream>>>(r2, src, dstp, ew, dinv, out, c0, E);
  }

  // epilogue: sigmoid(out + b1)
  nb = (N * 16 + 255) / 256;
  bias_sigmoid<<<nb, 256, 0, stream>>>(out, b1, N);
}

// Round 3
// 1149.934 us; speedup vs baseline: 7.1591x; 7.1591x over previous
//
#include <hip/hip_runtime.h>
#include <math.h>

// ================= shared small kernels =================

__global__ __launch_bounds__(256) void zero_f32(float* __restrict__ p, int n) {
  int i = blockIdx.x * 256 + threadIdx.x;
  if (i < n) p[i] = 0.f;
}

__global__ __launch_bounds__(256) void deg_accum(const int* __restrict__ dst,
                                                 const float* __restrict__ ew,
                                                 float* __restrict__ deg, int E) {
  int i = blockIdx.x * 256 + threadIdx.x;
  if (i < E) atomicAdd(&deg[dst[i]], ew[i]);
}

// fused: weighted degree + edge count histogram (CSR path)
__global__ __launch_bounds__(256) void deg_count(const int* __restrict__ dst,
                                                 const float* __restrict__ ew,
                                                 float* __restrict__ deg,
                                                 int* __restrict__ count, int E) {
  int i = blockIdx.x * 256 + threadIdx.x;
  if (i < E) {
    int d = dst[i];
    atomicAdd(&deg[d], ew[i]);
    atomicAdd(&count[d], 1);
  }
}

__global__ __launch_bounds__(256) void deg_to_dinv(float* __restrict__ d, int n) {
  int i = blockIdx.x * 256 + threadIdx.x;
  if (i < n) d[i] = rsqrtf(d[i] + 2.0f);  // + self-loop weight 2.0; deg >= 2 always
}

// ================= 3-kernel exclusive scan over count[N] -> row_start =================

__global__ __launch_bounds__(256) void scan_bsum(const int* __restrict__ count,
                                                 int* __restrict__ bsum, int N) {
  __shared__ int sm[256];
  int i = blockIdx.x * 256 + threadIdx.x;
  sm[threadIdx.x] = (i < N) ? count[i] : 0;
  __syncthreads();
  for (int off = 128; off > 0; off >>= 1) {
    if (threadIdx.x < off) sm[threadIdx.x] += sm[threadIdx.x + off];
    __syncthreads();
  }
  if (threadIdx.x == 0) bsum[blockIdx.x] = sm[0];
}

__global__ __launch_bounds__(512) void scan_bscan(int* __restrict__ bsum, int nblk) {
  // single block: exclusive scan of bsum[0..nblk), nblk <= 512
  __shared__ int sm[512];
  int t = threadIdx.x;
  int v = (t < nblk) ? bsum[t] : 0;
  sm[t] = v;
  __syncthreads();
  for (int off = 1; off < 512; off <<= 1) {
    int a = (t >= off) ? sm[t - off] : 0;
    __syncthreads();
    sm[t] += a;
    __syncthreads();
  }
  if (t < nblk) bsum[t] = sm[t] - v;  // exclusive
}

__global__ __launch_bounds__(256) void scan_final(const int* __restrict__ count,
                                                  const int* __restrict__ bscan,
                                                  int* __restrict__ row_start, int N) {
  __shared__ int sm[256];
  int i = blockIdx.x * 256 + threadIdx.x;
  int t = threadIdx.x;
  int v = (i < N) ? count[i] : 0;
  sm[t] = v;
  __syncthreads();
  for (int off = 1; off < 256; off <<= 1) {
    int a = (t >= off) ? sm[t - off] : 0;
    __syncthreads();
    sm[t] += a;
    __syncthreads();
  }
  int excl = sm[t] - v + bscan[blockIdx.x];
  if (i < N) row_start[i] = excl;
  if (i == N - 1) row_start[N] = excl + v;  // total = E
}

// ================= CSR fill: rec = (src<<15) | q15(ew*dinv[src]) =================
// max v = ew*dinv[src] < 1.0 * rsqrt(2) = 0.7072 < 0.75 -> q fits 15 bits.

__global__ __launch_bounds__(256) void csr_fill(const int* __restrict__ src,
                                                const int* __restrict__ dst,
                                                const float* __restrict__ ew,
                                                const float* __restrict__ dinv,
                                                const int* __restrict__ row_start,
                                                int* __restrict__ cursor,
                                                unsigned int* __restrict__ recs, int E) {
  int i = blockIdx.x * 256 + threadIdx.x;
  if (i >= E) return;
  int s = src[i], d = dst[i];
  float v = ew[i] * dinv[s];
  int q = (int)(v * (32767.f / 0.75f) + 0.5f);
  q = (q < 0) ? 0 : ((q > 32767) ? 32767 : q);
  int pos = row_start[d] + atomicAdd(&cursor[d], 1);
  recs[pos] = ((unsigned int)s << 15) | (unsigned int)q;
}

// ================= layer-1 gather: xa[d] = 2*dinv[d]^2 * x[d] + sum cf*x[src] =================
// one wave (64 lanes) per dst node; float2 per lane covers 128 cols; 512B coalesced row reads.

__global__ __launch_bounds__(256) void gather_l1(const float* __restrict__ x,
                                                 const unsigned int* __restrict__ recs,
                                                 const int* __restrict__ row_start,
                                                 const float* __restrict__ dinv,
                                                 float* __restrict__ xa, int N) {
  const int lane = threadIdx.x & 63;
  const int d = blockIdx.x * 4 + (threadIdx.x >> 6);
  if (d >= N) return;
  const int beg = row_start[d], end = row_start[d + 1];
  const float dd = dinv[d];
  float2 acc = *(const float2*)&x[(long)d * 128 + lane * 2];
  const float sl = 2.f * dd * dd;
  acc.x *= sl;
  acc.y *= sl;
  for (int j = beg; j < end; ++j) {
    const unsigned int rec = recs[j];  // wave-uniform -> scalar load
    const int s = rec >> 15;
    const float cf = (float)(rec & 32767u) * (0.75f / 32767.f) * dd;
    const float2 xv = *(const float2*)&x[(long)s * 128 + lane * 2];
    acc.x = fmaf(cf, xv.x, acc.x);
    acc.y = fmaf(cf, xv.y, acc.y);
  }
  *(float2*)&xa[(long)d * 128 + lane * 2] = acc;
}

// ================= layer-2 tile gather (16 cols): out[d, c0:c0+16] = Ahat @ r2 =================
// 4 threads per dst node, float4 each.

__global__ __launch_bounds__(256) void gather_l2_t16(const float* __restrict__ r2,
                                                     const unsigned int* __restrict__ recs,
                                                     const int* __restrict__ row_start,
                                                     const float* __restrict__ dinv,
                                                     float* __restrict__ out, int c0,
                                                     int N) {
  const int t = blockIdx.x * 256 + threadIdx.x;
  const int d = t >> 2;
  if (d >= N) return;
  const int c = (t & 3) * 4;
  const int beg = row_start[d], end = row_start[d + 1];
  const float dd = dinv[d];
  float4 acc = *(const float4*)&r2[(long)d * 16 + c];
  const float sl = 2.f * dd * dd;
  acc.x *= sl; acc.y *= sl; acc.z *= sl; acc.w *= sl;
  for (int j = beg; j < end; ++j) {
    const unsigned int rec = recs[j];
    const int s = rec >> 15;
    const float cf = (float)(rec & 32767u) * (0.75f / 32767.f) * dd;
    const float4 rv = *(const float4*)&r2[(long)s * 16 + c];
    acc.x = fmaf(cf, rv.x, acc.x);
    acc.y = fmaf(cf, rv.y, acc.y);
    acc.z = fmaf(cf, rv.z, acc.z);
    acc.w = fmaf(cf, rv.w, acc.w);
  }
  *(float4*)&out[(long)d * 64 + c0 + c] = acc;
}

// ================= atomic-path kernels (round-2 fallback, proven) =================

template <int F>
__global__ __launch_bounds__(256) void selfloop(const float* __restrict__ in,
                                                const float* __restrict__ dinv,
                                                float* __restrict__ out, int N) {
  int i = blockIdx.x * 256 + threadIdx.x;
  int total = N * (F / 4);
  if (i >= total) return;
  int n = i / (F / 4);
  float dv = dinv[n];
  float s = 2.f * dv * dv;
  float4 v = *(const float4*)&in[(long)i * 4];
  v.x *= s; v.y *= s; v.z *= s; v.w *= s;
  *(float4*)&out[(long)i * 4] = v;
}

template <int F>
__global__ __launch_bounds__(256) void scatter(const float* __restrict__ in,
                                               const int* __restrict__ src,
                                               const int* __restrict__ dst,
                                               const float* __restrict__ ew,
                                               const float* __restrict__ dinv,
                                               float* __restrict__ out, int E) {
  constexpr int TPE = F / 4;
  constexpr int EPB = 256 / TPE;
  const int lane = threadIdx.x % TPE;
  const long e = (long)blockIdx.x * EPB + threadIdx.x / TPE;
  if (e >= E) return;
  const int s = src[e], d = dst[e];
  const float cf = dinv[s] * ew[e] * dinv[d];
  const float4 hv = *(const float4*)&in[(long)s * F + lane * 4];
  float* o = &out[(long)d * F + lane * 4];
  atomicAdd(o + 0, hv.x * cf);
  atomicAdd(o + 1, hv.y * cf);
  atomicAdd(o + 2, hv.z * cf);
  atomicAdd(o + 3, hv.w * cf);
}

__global__ __launch_bounds__(256) void selfloop_t16(const float* __restrict__ r2,
                                                    const float* __restrict__ dinv,
                                                    float* __restrict__ out, int c0,
                                                    int N) {
  int i = blockIdx.x * 256 + threadIdx.x;
  if (i >= N * 4) return;
  int n = i >> 2;
  int c = (i & 3) * 4;
  float dv = dinv[n];
  float s = 2.f * dv * dv;
  float4 v = *(const float4*)&r2[(long)n * 16 + c];
  v.x *= s; v.y *= s; v.z *= s; v.w *= s;
  *(float4*)&out[(long)n * 64 + c0 + c] = v;
}

__global__ __launch_bounds__(256) void scatter_t16(const float* __restrict__ r2,
                                                   const int* __restrict__ src,
                                                   const int* __restrict__ dst,
                                                   const float* __restrict__ ew,
                                                   const float* __restrict__ dinv,
                                                   float* __restrict__ out, int c0,
                                                   int E) {
  const int lane = threadIdx.x & 3;
  const long e = (long)blockIdx.x * 64 + (threadIdx.x >> 2);
  if (e >= E) return;
  const int s = src[e], d = dst[e];
  const float cf = dinv[s] * ew[e] * dinv[d];
  const float4 hv = *(const float4*)&r2[(long)s * 16 + lane * 4];
  float* o = &out[(long)d * 64 + c0 + lane * 4];
  atomicAdd(o + 0, hv.x * cf);
  atomicAdd(o + 1, hv.y * cf);
  atomicAdd(o + 2, hv.z * cf);
  atomicAdd(o + 3, hv.w * cf);
}

// ================= GEMMs =================

__global__ __launch_bounds__(256) void gemm_inplace128(float* __restrict__ A,
                                                       const float* __restrict__ W,
                                                       int N) {
  __shared__ float Al[64][128];
  __shared__ float Wl[128][64];
  const int row0 = blockIdx.x * 64;
  for (int i = threadIdx.x * 4; i < 64 * 128; i += 1024) {
    int r = i >> 7, k = i & 127;
    float4 v = make_float4(0.f, 0.f, 0.f, 0.f);
    if (row0 + r < N) v = *(const float4*)&A[(long)(row0 + r) * 128 + k];
    *(float4*)&Al[r][k] = v;
  }
  __syncthreads();
  const int cg = threadIdx.x & 15;
  const int rg = threadIdx.x >> 4;
  const int c = cg * 4, r0 = rg * 4;
  for (int ct = 0; ct < 2; ++ct) {
    for (int i = threadIdx.x * 4; i < 128 * 64; i += 1024) {
      int k = i >> 6, cc = i & 63;
      *(float4*)&Wl[k][cc] = *(const float4*)&W[(long)k * 128 + ct * 64 + cc];
    }
    __syncthreads();
    float acc[4][4] = {};
#pragma unroll 4
    for (int k = 0; k < 128; ++k) {
      const float4 w = *(const float4*)&Wl[k][c];
#pragma unroll
      for (int i = 0; i < 4; ++i) {
        const float a = Al[r0 + i][k];
        acc[i][0] = fmaf(a, w.x, acc[i][0]);
        acc[i][1] = fmaf(a, w.y, acc[i][1]);
        acc[i][2] = fmaf(a, w.z, acc[i][2]);
        acc[i][3] = fmaf(a, w.w, acc[i][3]);
      }
    }
#pragma unroll
    for (int i = 0; i < 4; ++i) {
      int r = row0 + r0 + i;
      if (r < N)
        *(float4*)&A[(long)r * 128 + ct * 64 + c] =
            make_float4(acc[i][0], acc[i][1], acc[i][2], acc[i][3]);
    }
    __syncthreads();
  }
}

__global__ __launch_bounds__(256) void gemm_tile16(const float* __restrict__ A,
                                                   const float* __restrict__ bias,
                                                   const float* __restrict__ W,
                                                   int c0, float* __restrict__ r2,
                                                   int N) {
  __shared__ float Al[64][132];
  __shared__ float Wl[128][16];
  const int row0 = blockIdx.x * 64;
  for (int i = threadIdx.x * 4; i < 64 * 128; i += 1024) {
    int r = i >> 7, k = i & 127;
    float4 v = make_float4(0.f, 0.f, 0.f, 0.f);
    if (row0 + r < N) {
      v = *(const float4*)&A[(long)(row0 + r) * 128 + k];
      const float4 b = *(const float4*)&bias[k];
      v.x = fmaxf(v.x + b.x, 0.f);
      v.y = fmaxf(v.y + b.y, 0.f);
      v.z = fmaxf(v.z + b.z, 0.f);
      v.w = fmaxf(v.w + b.w, 0.f);
    }
    *(float4*)&Al[r][k] = v;
  }
  for (int i = threadIdx.x * 4; i < 128 * 16; i += 1024) {
    int k = i >> 4, cc = i & 15;
    *(float4*)&Wl[k][cc] = *(const float4*)&W[(long)k * 64 + c0 + cc];
  }
  __syncthreads();
  const int rg = threadIdx.x >> 2;
  const int c = (threadIdx.x & 3) * 4;
  float acc[4] = {0.f, 0.f, 0.f, 0.f};
#pragma unroll 4
  for (int k = 0; k < 128; ++k) {
    const float4 w = *(const float4*)&Wl[k][c];
    const float a = Al[rg][k];
    acc[0] = fmaf(a, w.x, acc[0]);
    acc[1] = fmaf(a, w.y, acc[1]);
    acc[2] = fmaf(a, w.z, acc[2]);
    acc[3] = fmaf(a, w.w, acc[3]);
  }
  if (row0 + rg < N)
    *(float4*)&r2[(long)(row0 + rg) * 16 + c] =
        make_float4(acc[0], acc[1], acc[2], acc[3]);
}

__global__ __launch_bounds__(256) void bias_sigmoid(float* __restrict__ io,
                                                    const float* __restrict__ bias,
                                                    int N) {
  int i = blockIdx.x * 256 + threadIdx.x;
  if (i >= N * 16) return;
  int c4 = (i & 15) * 4;
  float4 v = *(float4*)&io[(long)i * 4];
  const float4 b = *(const float4*)&bias[c4];
  v.x = 1.f / (1.f + __expf(-(v.x + b.x)));
  v.y = 1.f / (1.f + __expf(-(v.y + b.y)));
  v.z = 1.f / (1.f + __expf(-(v.z + b.z)));
  v.w = 1.f / (1.f + __expf(-(v.w + b.w)));
  *(float4*)&io[(long)i * 4] = v;
}

// ================= launch =================
// out = sigmoid( Ahat @ (relu(Ahat @ x @ W0 + b0) @ W1) + b1 ), Ahat = D^-1/2 (A+2I) D^-1/2.
// Layer 1 uses (Ahat x) W0 == Ahat (x W0). Aggregation via per-call CSR gather when the
// workspace fits (~71.6 MB); else the proven atomic-scatter path (~58.8 MB).

extern "C" void kernel_launch(void* const* d_in, const int* in_sizes, int n_in,
                              void* d_out, int out_size, void* d_ws, size_t ws_size,
                              hipStream_t stream) {
  const float* x  = (const float*)d_in[0];
  const int* src  = (const int*)d_in[1];
  const float* ew = (const float*)d_in[2];
  const float* W0 = (const float*)d_in[3];
  const float* b0 = (const float*)d_in[4];
  const float* W1 = (const float*)d_in[5];
  const float* b1 = (const float*)d_in[6];
  float* out = (float*)d_out;

  const int N = in_sizes[0] / 128;
  const int E = in_sizes[2];
  const int* dstp = src + E;

  float* ws = (float*)d_ws;
  const size_t oN = ((size_t)N + 255) & ~(size_t)255;

  // CSR layout (4B units): dinv[oN] | buf1[N*128] | r2[N*16] | row_start[oN] |
  //                        cursor[oN] | bsum[1024] | recs[E]
  const size_t csr_units = oN * 3 + (size_t)N * 144 + 1024 + (size_t)E;
  const bool use_csr = ws_size >= csr_units * 4;

  float* dinv = ws;
  float* buf1 = ws + oN;

  int nb;
  const int nbN = (N + 255) / 256;
  const int nbE = (E + 255) / 256;

  if (use_csr) {
    float* r2 = buf1 + (size_t)N * 128;
    int* row_start = (int*)(r2 + (size_t)N * 16);
    int* cursor = row_start + oN;
    int* bsum = cursor + oN;
    unsigned int* recs = (unsigned int*)(bsum + 1024);

    // deg + count histogram
    zero_f32<<<nbN, 256, 0, stream>>>(dinv, N);
    zero_f32<<<nbN, 256, 0, stream>>>((float*)cursor, N);  // count, reused as cursor later
    deg_count<<<nbE, 256, 0, stream>>>(dstp, ew, dinv, cursor, E);
    deg_to_dinv<<<nbN, 256, 0, stream>>>(dinv, N);

    // scan count -> row_start (exclusive), total at row_start[N]
    const int nblk1 = (N + 255) / 256;  // <= 512 for N <= 131072
    scan_bsum<<<nblk1, 256, 0, stream>>>(cursor, bsum, N);
    scan_bscan<<<1, 512, 0, stream>>>(bsum, nblk1);
    scan_final<<<nblk1, 256, 0, stream>>>(cursor, bsum, row_start, N);

    // fill records
    zero_f32<<<nbN, 256, 0, stream>>>((float*)cursor, N);
    csr_fill<<<nbE, 256, 0, stream>>>(src, dstp, ew, dinv, row_start, cursor, recs, E);

    // layer 1: xa = Ahat @ x  (gather), then h1 = xa @ W0 in place
    gather_l1<<<(N + 3) / 4, 256, 0, stream>>>(x, recs, row_start, dinv, buf1, N);
    gemm_inplace128<<<(N + 63) / 64, 256, 0, stream>>>(buf1, W0, N);

    // layer 2 in four 16-col tiles: r2 = relu(h1+b0) @ W1[:,c0:], out-tile = Ahat @ r2
    for (int t = 0; t < 4; ++t) {
      const int c0 = t * 16;
      gemm_tile16<<<(N + 63) / 64, 256, 0, stream>>>(buf1, b0, W1, c0, r2, N);
      gather_l2_t16<<<(N * 4 + 255) / 256, 256, 0, stream>>>(r2, recs, row_start, dinv,
                                                             out, c0, N);
    }
  } else {
    // -------- fallback: proven round-2 atomic path (58.8 MB) --------
    float* r2 = buf1 + (size_t)N * 128;

    zero_f32<<<nbN, 256, 0, stream>>>(dinv, N);
    deg_accum<<<nbE, 256, 0, stream>>>(dstp, ew, dinv, E);
    deg_to_dinv<<<nbN, 256, 0, stream>>>(dinv, N);

    nb = (N * 32 + 255) / 256;
    selfloop<128><<<nb, 256, 0, stream>>>(x, dinv, buf1, N);
    nb = (E + 7) / 8;
    scatter<128><<<nb, 256, 0, stream>>>(x, src, dstp, ew, dinv, buf1, E);

    gemm_inplace128<<<(N + 63) / 64, 256, 0, stream>>>(buf1, W0, N);

    for (int t = 0; t < 4; ++t) {
      const int c0 = t * 16;
      gemm_tile16<<<(N + 63) / 64, 256, 0, stream>>>(buf1, b0, W1, c0, r2, N);
      nb = (N * 4 + 255) / 256;
      selfloop_t16<<<nb, 256, 0, stream>>>(r2, dinv, out, c0, N);
      nb = (E + 63) / 64;
      scatter_t16<<<nb, 256, 0, stream>>>(r2, src, dstp, ew, dinv, out, c0, E);
    }
  }

  // epilogue: sigmoid(out + b1)
  nb = (N * 16 + 255) / 256;
  bias_sigmoid<<<nb, 256, 0, stream>>>(out, b1, N);
}

// Round 4
// 998.901 us; speedup vs baseline: 8.2415x; 1.1512x over previous
//
#include <hip/hip_runtime.h>
#include <math.h>

// ---------------- bf16 helpers (RNE) ----------------

__device__ __forceinline__ unsigned short f2b(float f) {
  unsigned u = __float_as_uint(f);
  unsigned r = u + 0x7fffu + ((u >> 16) & 1u);
  return (unsigned short)(r >> 16);
}
__device__ __forceinline__ float b2f_lo(unsigned v) {
  return __uint_as_float(v << 16);
}
__device__ __forceinline__ float b2f_hi(unsigned v) {
  return __uint_as_float(v & 0xffff0000u);
}

// ---------------- small kernels ----------------

__global__ __launch_bounds__(256) void zero_f32(float* __restrict__ p, int n) {
  int i = blockIdx.x * 256 + threadIdx.x;
  if (i < n) p[i] = 0.f;
}

// fused: weighted degree + edge count histogram
__global__ __launch_bounds__(256) void deg_count(const int* __restrict__ dst,
                                                 const float* __restrict__ ew,
                                                 float* __restrict__ deg,
                                                 int* __restrict__ count, int E) {
  int i = blockIdx.x * 256 + threadIdx.x;
  if (i < E) {
    int d = dst[i];
    atomicAdd(&deg[d], ew[i]);
    atomicAdd(&count[d], 1);
  }
}

__global__ __launch_bounds__(256) void deg_to_dinv(float* __restrict__ d, int n) {
  int i = blockIdx.x * 256 + threadIdx.x;
  if (i < n) d[i] = rsqrtf(d[i] + 2.0f);  // + self-loop weight 2.0; deg >= 2 always
}

// x (f32) -> xb (bf16), 8 elements/thread
__global__ __launch_bounds__(256) void to_bf16_8(const float* __restrict__ x,
                                                 unsigned short* __restrict__ xb,
                                                 int n8) {
  int i = blockIdx.x * 256 + threadIdx.x;
  if (i >= n8) return;
  const float4 a = *(const float4*)&x[(long)i * 8];
  const float4 b = *(const float4*)&x[(long)i * 8 + 4];
  uint4 o;
  o.x = (unsigned)f2b(a.x) | ((unsigned)f2b(a.y) << 16);
  o.y = (unsigned)f2b(a.z) | ((unsigned)f2b(a.w) << 16);
  o.z = (unsigned)f2b(b.x) | ((unsigned)f2b(b.y) << 16);
  o.w = (unsigned)f2b(b.z) | ((unsigned)f2b(b.w) << 16);
  *(uint4*)&xb[(long)i * 8] = o;
}

// ---------------- 3-kernel exclusive scan over count[N] -> row_start ----------------

__global__ __launch_bounds__(256) void scan_bsum(const int* __restrict__ count,
                                                 int* __restrict__ bsum, int N) {
  __shared__ int sm[256];
  int i = blockIdx.x * 256 + threadIdx.x;
  sm[threadIdx.x] = (i < N) ? count[i] : 0;
  __syncthreads();
  for (int off = 128; off > 0; off >>= 1) {
    if (threadIdx.x < off) sm[threadIdx.x] += sm[threadIdx.x + off];
    __syncthreads();
  }
  if (threadIdx.x == 0) bsum[blockIdx.x] = sm[0];
}

__global__ __launch_bounds__(512) void scan_bscan(int* __restrict__ bsum, int nblk) {
  __shared__ int sm[512];
  int t = threadIdx.x;
  int v = (t < nblk) ? bsum[t] : 0;
  sm[t] = v;
  __syncthreads();
  for (int off = 1; off < 512; off <<= 1) {
    int a = (t >= off) ? sm[t - off] : 0;
    __syncthreads();
    sm[t] += a;
    __syncthreads();
  }
  if (t < nblk) bsum[t] = sm[t] - v;  // exclusive
}

__global__ __launch_bounds__(256) void scan_final(const int* __restrict__ count,
                                                  const int* __restrict__ bscan,
                                                  int* __restrict__ row_start, int N) {
  __shared__ int sm[256];
  int i = blockIdx.x * 256 + threadIdx.x;
  int t = threadIdx.x;
  int v = (i < N) ? count[i] : 0;
  sm[t] = v;
  __syncthreads();
  for (int off = 1; off < 256; off <<= 1) {
    int a = (t >= off) ? sm[t - off] : 0;
    __syncthreads();
    sm[t] += a;
    __syncthreads();
  }
  int excl = sm[t] - v + bscan[blockIdx.x];
  if (i < N) row_start[i] = excl;
  if (i == N - 1) row_start[N] = excl + v;
}

// ---------------- CSR fill: rec = (src<<15) | q15(ew*dinv[src]) ----------------
// max ew*dinv[src] < 1.0*rsqrt(2) < 0.75 -> 15-bit fixed point, rel err ~1.5e-5.

__global__ __launch_bounds__(256) void csr_fill(const int* __restrict__ src,
                                                const int* __restrict__ dst,
                                                const float* __restrict__ ew,
                                                const float* __restrict__ dinv,
                                                const int* __restrict__ row_start,
                                                int* __restrict__ cursor,
                                                unsigned int* __restrict__ recs, int E) {
  int i = blockIdx.x * 256 + threadIdx.x;
  if (i >= E) return;
  int s = src[i], d = dst[i];
  float v = ew[i] * dinv[s];
  int q = (int)(v * (32767.f / 0.75f) + 0.5f);
  q = (q < 0) ? 0 : ((q > 32767) ? 32767 : q);
  int pos = row_start[d] + atomicAdd(&cursor[d], 1);
  recs[pos] = ((unsigned int)s << 15) | (unsigned int)q;
}

// ---------------- layer-1 gather (bf16 payload): xa_b[d] = bf16( Ahat-row-d @ x ) ----------------
// one wave per dst node; lane covers 2 cols via one uint (2 bf16); 256B coalesced rows.

__global__ __launch_bounds__(256) void gather_l1(const unsigned int* __restrict__ xb,
                                                 const unsigned int* __restrict__ recs,
                                                 const int* __restrict__ row_start,
                                                 const float* __restrict__ dinv,
                                                 unsigned int* __restrict__ xab, int N) {
  const int lane = threadIdx.x & 63;
  const int d = blockIdx.x * 4 + (threadIdx.x >> 6);
  if (d >= N) return;
  const int beg = row_start[d], end = row_start[d + 1];
  const float dd = dinv[d];
  const unsigned sv = xb[(long)d * 64 + lane];
  const float sl = 2.f * dd * dd;
  float acc0 = b2f_lo(sv) * sl;
  float acc1 = b2f_hi(sv) * sl;
  for (int j = beg; j < end; ++j) {
    const unsigned rec = recs[j];
    const int s = rec >> 15;
    const float cf = (float)(rec & 32767u) * (0.75f / 32767.f) * dd;
    const unsigned v = xb[(long)s * 64 + lane];
    acc0 = fmaf(cf, b2f_lo(v), acc0);
    acc1 = fmaf(cf, b2f_hi(v), acc1);
  }
  xab[(long)d * 64 + lane] = (unsigned)f2b(acc0) | ((unsigned)f2b(acc1) << 16);
}

// ---------------- fused MLP: r2b = bf16( relu(xa@W0 + b0) @ W1 ) ----------------
// 64-row tile per block. h1 never hits HBM. W staged in 32-col quarters (16 KB).
// LDS: Al 64x130 ushort (16.3K) + Wl 128x32 f32 (16K) + Hl 64x129 f32 (33K) = ~66 KB.

__global__ __launch_bounds__(256) void fused_mlp(const unsigned int* __restrict__ xab,
                                                 const float* __restrict__ W0,
                                                 const float* __restrict__ b0,
                                                 const float* __restrict__ W1,
                                                 unsigned int* __restrict__ r2b, int N) {
  __shared__ unsigned short Al[64][130];  // pad: bank=(r + k/2)%32 -> conflict-free
  __shared__ float Wl[128][32];
  __shared__ float Hl[64][129];           // pad: bank=(r + k)%32 -> conflict-free
  const int tid = threadIdx.x;
  const int row0 = blockIdx.x * 64;

  // stage xa_b tile: 64 rows x 64 uints
  for (int i = tid; i < 64 * 64; i += 256) {
    const int r = i >> 6, cu = i & 63;
    unsigned v = 0;
    if (row0 + r < N) v = xab[(long)(row0 + r) * 64 + cu];
    *(unsigned*)&Al[r][cu * 2] = v;
  }

  const int r = tid >> 2;       // 64 rows
  const int q = tid & 3;        // 4 col-groups
  // ---- h1 = xa @ W0 (+b0, relu) in 4 column-quarters of 32 ----
  for (int ph = 0; ph < 4; ++ph) {
    __syncthreads();
    for (int i = tid * 4; i < 128 * 32; i += 1024) {  // stage W0[:, ph*32 : +32]
      const int k = i >> 5, c = i & 31;
      *(float4*)&Wl[k][c] = *(const float4*)&W0[(long)k * 128 + ph * 32 + c];
    }
    __syncthreads();
    float acc[8] = {};
    for (int k = 0; k < 128; ++k) {
      const float a = b2f_lo((unsigned)Al[r][k] << 16 >> 16 | ((unsigned)Al[r][k] << 16));
      // (the above compiles to: convert Al[r][k] bf16 -> f32)
      const float av = __uint_as_float((unsigned)Al[r][k] << 16);
      const float4 w0 = *(const float4*)&Wl[k][q * 8];
      const float4 w1 = *(const float4*)&Wl[k][q * 8 + 4];
      acc[0] = fmaf(av, w0.x, acc[0]);
      acc[1] = fmaf(av, w0.y, acc[1]);
      acc[2] = fmaf(av, w0.z, acc[2]);
      acc[3] = fmaf(av, w0.w, acc[3]);
      acc[4] = fmaf(av, w1.x, acc[4]);
      acc[5] = fmaf(av, w1.y, acc[5]);
      acc[6] = fmaf(av, w1.z, acc[6]);
      acc[7] = fmaf(av, w1.w, acc[7]);
    }
    const int cbase = ph * 32 + q * 8;
#pragma unroll
    for (int c = 0; c < 8; ++c) {
      Hl[r][cbase + c] = fmaxf(acc[c] + b0[cbase + c], 0.f);
    }
  }

  // ---- r2 = Hl @ W1 in 2 column-halves of 32 ----
  for (int ph = 0; ph < 2; ++ph) {
    __syncthreads();
    for (int i = tid * 4; i < 128 * 32; i += 1024) {  // stage W1[:, ph*32 : +32]
      const int k = i >> 5, c = i & 31;
      *(float4*)&Wl[k][c] = *(const float4*)&W1[(long)k * 64 + ph * 32 + c];
    }
    __syncthreads();
    float acc[8] = {};
    for (int k = 0; k < 128; ++k) {
      const float a = Hl[r][k];
      const float4 w0 = *(const float4*)&Wl[k][q * 8];
      const float4 w1 = *(const float4*)&Wl[k][q * 8 + 4];
      acc[0] = fmaf(a, w0.x, acc[0]);
      acc[1] = fmaf(a, w0.y, acc[1]);
      acc[2] = fmaf(a, w0.z, acc[2]);
      acc[3] = fmaf(a, w0.w, acc[3]);
      acc[4] = fmaf(a, w1.x, acc[4]);
      acc[5] = fmaf(a, w1.y, acc[5]);
      acc[6] = fmaf(a, w1.z, acc[6]);
      acc[7] = fmaf(a, w1.w, acc[7]);
    }
    if (row0 + r < N) {
      uint2 o;
      o.x = (unsigned)f2b(acc[0]) | ((unsigned)f2b(acc[1]) << 16);
      o.y = (unsigned)f2b(acc[2]) | ((unsigned)f2b(acc[3]) << 16);
      uint2 o2;
      o2.x = (unsigned)f2b(acc[4]) | ((unsigned)f2b(acc[5]) << 16);
      o2.y = (unsigned)f2b(acc[6]) | ((unsigned)f2b(acc[7]) << 16);
      // row stride 64 bf16 = 32 uints
      *(uint2*)&r2b[(long)(row0 + r) * 32 + ph * 16 + q * 4] = o;
      *(uint2*)&r2b[(long)(row0 + r) * 32 + ph * 16 + q * 4 + 2] = o2;
    }
  }
}

// ---------------- layer-2 gather + b1 + sigmoid (fused epilogue) ----------------
// 16 lanes per dst node; lane covers 4 cols via uint2 (4 bf16).

__global__ __launch_bounds__(256) void gather_l2(const unsigned int* __restrict__ r2b,
                                                 const unsigned int* __restrict__ recs,
                                                 const int* __restrict__ row_start,
                                                 const float* __restrict__ dinv,
                                                 const float* __restrict__ b1,
                                                 float* __restrict__ out, int N) {
  const int t = blockIdx.x * 256 + threadIdx.x;
  const int d = t >> 4;
  if (d >= N) return;
  const int j = t & 15;
  const int beg = row_start[d], end = row_start[d + 1];
  const float dd = dinv[d];
  const uint2 sv = *(const uint2*)&r2b[(long)d * 32 + j * 2];
  const float sl = 2.f * dd * dd;
  float a0 = b2f_lo(sv.x) * sl, a1 = b2f_hi(sv.x) * sl;
  float a2 = b2f_lo(sv.y) * sl, a3 = b2f_hi(sv.y) * sl;
  for (int jj = beg; jj < end; ++jj) {
    const unsigned rec = recs[jj];
    const int s = rec >> 15;
    const float cf = (float)(rec & 32767u) * (0.75f / 32767.f) * dd;
    const uint2 v = *(const uint2*)&r2b[(long)s * 32 + j * 2];
    a0 = fmaf(cf, b2f_lo(v.x), a0);
    a1 = fmaf(cf, b2f_hi(v.x), a1);
    a2 = fmaf(cf, b2f_lo(v.y), a2);
    a3 = fmaf(cf, b2f_hi(v.y), a3);
  }
  const int c = j * 4;
  const float4 b = *(const float4*)&b1[c];
  float4 o;
  o.x = 1.f / (1.f + __expf(-(a0 + b.x)));
  o.y = 1.f / (1.f + __expf(-(a1 + b.y)));
  o.z = 1.f / (1.f + __expf(-(a2 + b.z)));
  o.w = 1.f / (1.f + __expf(-(a3 + b.w)));
  *(float4*)&out[(long)d * 64 + c] = o;
}

// ---------------- launch ----------------
// out = sigmoid( Ahat @ (relu((Ahat @ x) @ W0 + b0) @ W1) + b1 ),
// Ahat = D^-1/2 (A+2I) D^-1/2, using (Ahat x) W0 == Ahat (x W0).
// Gather payloads in bf16 (f32 accumulation); h1 kept on-chip (fused MLP).
// Workspace ~65.2 MB (< 71.6 MB proven available in round 3).

extern "C" void kernel_launch(void* const* d_in, const int* in_sizes, int n_in,
                              void* d_out, int out_size, void* d_ws, size_t ws_size,
                              hipStream_t stream) {
  const float* x  = (const float*)d_in[0];
  const int* src  = (const int*)d_in[1];
  const float* ew = (const float*)d_in[2];
  const float* W0 = (const float*)d_in[3];
  const float* b0 = (const float*)d_in[4];
  const float* W1 = (const float*)d_in[5];
  const float* b1 = (const float*)d_in[6];
  float* out = (float*)d_out;

  const int N = in_sizes[0] / 128;
  const int E = in_sizes[2];
  const int* dstp = src + E;

  // layout (4B units): dinv[oN] | row_start[oN] | cursor[oN] | bsum[1024] |
  //                    recs[E] | xb[N*64] | xab[N*64]      (r2b reuses xb)
  float* ws = (float*)d_ws;
  const size_t oN = ((size_t)N + 255) & ~(size_t)255;
  float* dinv = ws;
  int* row_start = (int*)(ws + oN);
  int* cursor = row_start + oN;
  int* bsum = cursor + oN;
  unsigned int* recs = (unsigned int*)(bsum + 1024);
  unsigned int* xb  = recs + E;                 // N*128 bf16 = N*64 uints
  unsigned int* xab = xb + (size_t)N * 64;
  unsigned int* r2b = xb;                       // reuse: xb dead after gather_l1

  const int nbN = (N + 255) / 256;
  const int nbE = (E + 255) / 256;

  // degree + count histogram -> dinv, row_start
  zero_f32<<<nbN, 256, 0, stream>>>(dinv, N);
  zero_f32<<<nbN, 256, 0, stream>>>((float*)cursor, N);
  deg_count<<<nbE, 256, 0, stream>>>(dstp, ew, dinv, cursor, E);
  deg_to_dinv<<<nbN, 256, 0, stream>>>(dinv, N);

  const int nblk1 = (N + 255) / 256;  // <= 512 for N <= 131072
  scan_bsum<<<nblk1, 256, 0, stream>>>(cursor, bsum, N);
  scan_bscan<<<1, 512, 0, stream>>>(bsum, nblk1);
  scan_final<<<nblk1, 256, 0, stream>>>(cursor, bsum, row_start, N);

  zero_f32<<<nbN, 256, 0, stream>>>((float*)cursor, N);
  csr_fill<<<nbE, 256, 0, stream>>>(src, dstp, ew, dinv, row_start, cursor, recs, E);

  // x -> bf16
  to_bf16_8<<<(N * 16 + 255) / 256, 256, 0, stream>>>(x, (unsigned short*)xb, N * 16);

  // layer 1 aggregate (gather) -> xa_b
  gather_l1<<<(N + 3) / 4, 256, 0, stream>>>(xb, recs, row_start, dinv, xab, N);

  // fused 2-layer MLP: r2b = relu(xa@W0+b0)@W1
  fused_mlp<<<(N + 63) / 64, 256, 0, stream>>>(xab, W0, b0, W1, r2b, N);

  // layer 2 aggregate + bias + sigmoid -> out
  gather_l2<<<(N * 16 + 255) / 256, 256, 0, stream>>>(r2b, recs, row_start, dinv, b1,
                                                      out, N);
}

// Round 5
// 714.554 us; speedup vs baseline: 11.5211x; 1.3979x over previous
//
#include <hip/hip_runtime.h>
#include <math.h>

// ---------------- bf16 helpers (RNE) ----------------

__device__ __forceinline__ unsigned short f2b(float f) {
  unsigned u = __float_as_uint(f);
  unsigned r = u + 0x7fffu + ((u >> 16) & 1u);
  return (unsigned short)(r >> 16);
}
__device__ __forceinline__ float b2f_lo(unsigned v) {
  return __uint_as_float(v << 16);
}
__device__ __forceinline__ float b2f_hi(unsigned v) {
  return __uint_as_float(v & 0xffff0000u);
}

// ---------------- small kernels ----------------

__global__ __launch_bounds__(256) void zero_f32(float* __restrict__ p, int n) {
  int i = blockIdx.x * 256 + threadIdx.x;
  if (i < n) p[i] = 0.f;
}

// one atomic per edge: in-row slot assignment + count histogram
__global__ __launch_bounds__(256) void count_slot(const int* __restrict__ dst,
                                                  int* __restrict__ count,
                                                  unsigned short* __restrict__ slot,
                                                  int E) {
  int i = blockIdx.x * 256 + threadIdx.x;
  if (i >= E) return;
  int p = atomicAdd(&count[dst[i]], 1);
  slot[i] = (unsigned short)p;  // max in-degree << 65536
}

// x (f32) -> xb (bf16), 8 elements/thread
__global__ __launch_bounds__(256) void to_bf16_8(const float* __restrict__ x,
                                                 unsigned short* __restrict__ xb,
                                                 int n8) {
  int i = blockIdx.x * 256 + threadIdx.x;
  if (i >= n8) return;
  const float4 a = *(const float4*)&x[(long)i * 8];
  const float4 b = *(const float4*)&x[(long)i * 8 + 4];
  uint4 o;
  o.x = (unsigned)f2b(a.x) | ((unsigned)f2b(a.y) << 16);
  o.y = (unsigned)f2b(a.z) | ((unsigned)f2b(a.w) << 16);
  o.z = (unsigned)f2b(b.x) | ((unsigned)f2b(b.y) << 16);
  o.w = (unsigned)f2b(b.z) | ((unsigned)f2b(b.w) << 16);
  *(uint4*)&xb[(long)i * 8] = o;
}

// ---------------- scan: count[N] -> exclusive row_start (in place) ----------------

__global__ __launch_bounds__(256) void scan_bsum(const int* __restrict__ count,
                                                 int* __restrict__ bsum, int N) {
  __shared__ int sm[256];
  int i = blockIdx.x * 256 + threadIdx.x;
  sm[threadIdx.x] = (i < N) ? count[i] : 0;
  __syncthreads();
  for (int off = 128; off > 0; off >>= 1) {
    if (threadIdx.x < off) sm[threadIdx.x] += sm[threadIdx.x + off];
    __syncthreads();
  }
  if (threadIdx.x == 0) bsum[blockIdx.x] = sm[0];
}

__global__ __launch_bounds__(512) void scan_bscan(int* __restrict__ bsum, int nblk) {
  __shared__ int sm[512];
  int t = threadIdx.x;
  int v = (t < nblk) ? bsum[t] : 0;
  sm[t] = v;
  __syncthreads();
  for (int off = 1; off < 512; off <<= 1) {
    int a = (t >= off) ? sm[t - off] : 0;
    __syncthreads();
    sm[t] += a;
    __syncthreads();
  }
  if (t < nblk) bsum[t] = sm[t] - v;  // exclusive
}

// in-place: cr[] holds count on entry, exclusive prefix (row_start) on exit; cr[N]=E.
__global__ __launch_bounds__(256) void scan_inplace(int* __restrict__ cr,
                                                    const int* __restrict__ bscan,
                                                    int N) {
  __shared__ int sm[256];
  int i = blockIdx.x * 256 + threadIdx.x;
  int t = threadIdx.x;
  int v = (i < N) ? cr[i] : 0;
  sm[t] = v;
  __syncthreads();
  for (int off = 1; off < 256; off <<= 1) {
    int a = (t >= off) ? sm[t - off] : 0;
    __syncthreads();
    sm[t] += a;
    __syncthreads();
  }
  int excl = sm[t] - v + bscan[blockIdx.x];
  if (i < N) cr[i] = excl;
  if (i == N - 1) cr[N] = excl + v;
}

// ---------------- atomic-free CSR fill: rec = (src<<15) | q15(ew) ----------------
// ew in [0,1] -> q = round(ew*32767) fits 15 bits; dequant scale 1/32767.

__global__ __launch_bounds__(256) void fill_recs(const int* __restrict__ src,
                                                 const int* __restrict__ dst,
                                                 const float* __restrict__ ew,
                                                 const unsigned short* __restrict__ slot,
                                                 const int* __restrict__ row_start,
                                                 unsigned int* __restrict__ recs, int E) {
  int i = blockIdx.x * 256 + threadIdx.x;
  if (i >= E) return;
  int q = (int)(ew[i] * 32767.f + 0.5f);
  q = (q < 0) ? 0 : ((q > 32767) ? 32767 : q);
  int pos = row_start[dst[i]] + (int)slot[i];
  recs[pos] = ((unsigned int)src[i] << 15) | (unsigned int)q;
}

// ---------------- atomic-free degree: dinv[d] = rsqrt(2 + sum_row q/32767) ----------------
// one wave per node; coalesced row reads + shuffle reduce.

__global__ __launch_bounds__(256) void deg_rows(const unsigned int* __restrict__ recs,
                                                const int* __restrict__ row_start,
                                                float* __restrict__ dinv, int N) {
  const int lane = threadIdx.x & 63;
  const int d = blockIdx.x * 4 + (threadIdx.x >> 6);
  if (d >= N) return;
  const int beg = row_start[d], end = row_start[d + 1];
  float s = 0.f;
  for (int j = beg + lane; j < end; j += 64) s += (float)(recs[j] & 32767u);
  for (int off = 32; off > 0; off >>= 1) s += __shfl_down(s, off, 64);
  if (lane == 0) dinv[d] = rsqrtf(s * (1.f / 32767.f) + 2.0f);
}

// ---------------- layer-1 gather (bf16 payload) ----------------
// one wave per dst node; lane covers 2 cols via one uint (2 bf16); 256B coalesced rows.

__global__ __launch_bounds__(256) void gather_l1(const unsigned int* __restrict__ xb,
                                                 const unsigned int* __restrict__ recs,
                                                 const int* __restrict__ row_start,
                                                 const float* __restrict__ dinv,
                                                 unsigned int* __restrict__ xab, int N) {
  const int lane = threadIdx.x & 63;
  const int d = blockIdx.x * 4 + (threadIdx.x >> 6);
  if (d >= N) return;
  const int beg = row_start[d], end = row_start[d + 1];
  const float dd = dinv[d];
  const unsigned sv = xb[(long)d * 64 + lane];
  const float sl = 2.f * dd * dd;
  float acc0 = b2f_lo(sv) * sl;
  float acc1 = b2f_hi(sv) * sl;
  for (int j = beg; j < end; ++j) {
    const unsigned rec = recs[j];  // wave-uniform
    const int s = rec >> 15;
    const float cf = (float)(rec & 32767u) * (1.f / 32767.f) * dinv[s] * dd;
    const unsigned v = xb[(long)s * 64 + lane];
    acc0 = fmaf(cf, b2f_lo(v), acc0);
    acc1 = fmaf(cf, b2f_hi(v), acc1);
  }
  xab[(long)d * 64 + lane] = (unsigned)f2b(acc0) | ((unsigned)f2b(acc1) << 16);
}

// ---------------- fused MLP: r2b = bf16( relu(xa@W0 + b0) @ W1 ) ----------------
// 64-row tile per block; h1 stays on-chip (bf16 LDS). ~49.7 KB LDS -> 3 blocks/CU.

__global__ __launch_bounds__(256) void fused_mlp(const unsigned int* __restrict__ xab,
                                                 const float* __restrict__ W0,
                                                 const float* __restrict__ b0,
                                                 const float* __restrict__ W1,
                                                 unsigned int* __restrict__ r2b, int N) {
  __shared__ unsigned short Al[64][130];  // bf16 xa tile (pad -> conflict-free)
  __shared__ float Wl[128][32];           // W column slab
  __shared__ unsigned short Hl[64][130];  // bf16 h1 tile
  const int tid = threadIdx.x;
  const int row0 = blockIdx.x * 64;

  for (int i = tid; i < 64 * 64; i += 256) {
    const int r = i >> 6, cu = i & 63;
    unsigned v = 0;
    if (row0 + r < N) v = xab[(long)(row0 + r) * 64 + cu];
    *(unsigned*)&Al[r][cu * 2] = v;
  }

  const int r = tid >> 2;  // 64 rows
  const int q = tid & 3;   // 4 col-groups of 8
  // ---- h1 = relu(xa @ W0 + b0) in 4 column-quarters of 32 ----
  for (int ph = 0; ph < 4; ++ph) {
    __syncthreads();
    for (int i = tid * 4; i < 128 * 32; i += 1024) {
      const int k = i >> 5, c = i & 31;
      *(float4*)&Wl[k][c] = *(const float4*)&W0[(long)k * 128 + ph * 32 + c];
    }
    __syncthreads();
    float acc[8] = {};
    for (int k = 0; k < 128; ++k) {
      const float av = __uint_as_float((unsigned)Al[r][k] << 16);
      const float4 w0 = *(const float4*)&Wl[k][q * 8];
      const float4 w1 = *(const float4*)&Wl[k][q * 8 + 4];
      acc[0] = fmaf(av, w0.x, acc[0]);
      acc[1] = fmaf(av, w0.y, acc[1]);
      acc[2] = fmaf(av, w0.z, acc[2]);
      acc[3] = fmaf(av, w0.w, acc[3]);
      acc[4] = fmaf(av, w1.x, acc[4]);
      acc[5] = fmaf(av, w1.y, acc[5]);
      acc[6] = fmaf(av, w1.z, acc[6]);
      acc[7] = fmaf(av, w1.w, acc[7]);
    }
    const int cbase = ph * 32 + q * 8;
#pragma unroll
    for (int c = 0; c < 8; c += 2) {
      const float h0 = fmaxf(acc[c] + b0[cbase + c], 0.f);
      const float h1v = fmaxf(acc[c + 1] + b0[cbase + c + 1], 0.f);
      *(unsigned*)&Hl[r][cbase + c] = (unsigned)f2b(h0) | ((unsigned)f2b(h1v) << 16);
    }
  }

  // ---- r2 = h1 @ W1 in 2 column-halves of 32 ----
  for (int ph = 0; ph < 2; ++ph) {
    __syncthreads();
    for (int i = tid * 4; i < 128 * 32; i += 1024) {
      const int k = i >> 5, c = i & 31;
      *(float4*)&Wl[k][c] = *(const float4*)&W1[(long)k * 64 + ph * 32 + c];
    }
    __syncthreads();
    float acc[8] = {};
    for (int k = 0; k < 128; ++k) {
      const float a = __uint_as_float((unsigned)Hl[r][k] << 16);
      const float4 w0 = *(const float4*)&Wl[k][q * 8];
      const float4 w1 = *(const float4*)&Wl[k][q * 8 + 4];
      acc[0] = fmaf(a, w0.x, acc[0]);
      acc[1] = fmaf(a, w0.y, acc[1]);
      acc[2] = fmaf(a, w0.z, acc[2]);
      acc[3] = fmaf(a, w0.w, acc[3]);
      acc[4] = fmaf(a, w1.x, acc[4]);
      acc[5] = fmaf(a, w1.y, acc[5]);
      acc[6] = fmaf(a, w1.z, acc[6]);
      acc[7] = fmaf(a, w1.w, acc[7]);
    }
    if (row0 + r < N) {
      uint2 o, o2;
      o.x = (unsigned)f2b(acc[0]) | ((unsigned)f2b(acc[1]) << 16);
      o.y = (unsigned)f2b(acc[2]) | ((unsigned)f2b(acc[3]) << 16);
      o2.x = (unsigned)f2b(acc[4]) | ((unsigned)f2b(acc[5]) << 16);
      o2.y = (unsigned)f2b(acc[6]) | ((unsigned)f2b(acc[7]) << 16);
      *(uint2*)&r2b[(long)(row0 + r) * 32 + ph * 16 + q * 4] = o;
      *(uint2*)&r2b[(long)(row0 + r) * 32 + ph * 16 + q * 4 + 2] = o2;
    }
  }
}

// ---------------- layer-2 gather + b1 + sigmoid ----------------
// 16 lanes per dst node; lane covers 4 cols via uint2 (4 bf16).

__global__ __launch_bounds__(256) void gather_l2(const unsigned int* __restrict__ r2b,
                                                 const unsigned int* __restrict__ recs,
                                                 const int* __restrict__ row_start,
                                                 const float* __restrict__ dinv,
                                                 const float* __restrict__ b1,
                                                 float* __restrict__ out, int N) {
  const int t = blockIdx.x * 256 + threadIdx.x;
  const int d = t >> 4;
  if (d >= N) return;
  const int j = t & 15;
  const int beg = row_start[d], end = row_start[d + 1];
  const float dd = dinv[d];
  const uint2 sv = *(const uint2*)&r2b[(long)d * 32 + j * 2];
  const float sl = 2.f * dd * dd;
  float a0 = b2f_lo(sv.x) * sl, a1 = b2f_hi(sv.x) * sl;
  float a2 = b2f_lo(sv.y) * sl, a3 = b2f_hi(sv.y) * sl;
  for (int jj = beg; jj < end; ++jj) {
    const unsigned rec = recs[jj];
    const int s = rec >> 15;
    const float cf = (float)(rec & 32767u) * (1.f / 32767.f) * dinv[s] * dd;
    const uint2 v = *(const uint2*)&r2b[(long)s * 32 + j * 2];
    a0 = fmaf(cf, b2f_lo(v.x), a0);
    a1 = fmaf(cf, b2f_hi(v.x), a1);
    a2 = fmaf(cf, b2f_lo(v.y), a2);
    a3 = fmaf(cf, b2f_hi(v.y), a3);
  }
  const int c = j * 4;
  const float4 b = *(const float4*)&b1[c];
  float4 o;
  o.x = 1.f / (1.f + __expf(-(a0 + b.x)));
  o.y = 1.f / (1.f + __expf(-(a1 + b.y)));
  o.z = 1.f / (1.f + __expf(-(a2 + b.z)));
  o.w = 1.f / (1.f + __expf(-(a3 + b.w)));
  *(float4*)&out[(long)d * 64 + c] = o;
}

// ---------------- launch ----------------
// out = sigmoid( Ahat @ (relu((Ahat @ x) @ W0 + b0) @ W1) + b1 ),
// Ahat = D^-1/2 (A+2I) D^-1/2, using (Ahat x) W0 == Ahat (x W0).
// CSR built with ONE atomic per edge (count+slot); fill and degree are atomic-free.
// Workspace ~71.2 MB (< 71.6 MB proven available in round 3).

extern "C" void kernel_launch(void* const* d_in, const int* in_sizes, int n_in,
                              void* d_out, int out_size, void* d_ws, size_t ws_size,
                              hipStream_t stream) {
  const float* x  = (const float*)d_in[0];
  const int* src  = (const int*)d_in[1];
  const float* ew = (const float*)d_in[2];
  const float* W0 = (const float*)d_in[3];
  const float* b0 = (const float*)d_in[4];
  const float* W1 = (const float*)d_in[5];
  const float* b1 = (const float*)d_in[6];
  float* out = (float*)d_out;

  const int N = in_sizes[0] / 128;
  const int E = in_sizes[2];
  const int* dstp = src + E;

  // layout (4B units): dinv[oN] | rowst[oN] (count->row_start in place) | bsum[1024]
  //                  | recs[E] | slot[E ushort] | xb[N*64] | xab[N*64]  (r2b reuses xb)
  float* ws = (float*)d_ws;
  const size_t oN = ((size_t)N + 255) & ~(size_t)255;
  float* dinv = ws;
  int* rowst = (int*)(ws + oN);
  int* bsum = rowst + oN;
  unsigned int* recs = (unsigned int*)(bsum + 1024);
  unsigned short* slot = (unsigned short*)(recs + E);
  unsigned int* xb = recs + E + ((size_t)E + 1) / 2;
  unsigned int* xab = xb + (size_t)N * 64;
  unsigned int* r2b = xb;  // xb dead after gather_l1

  const int nbN = (N + 255) / 256;
  const int nbE = (E + 255) / 256;

  // CSR build: count+slot (1 atomic/edge) -> scan -> fill -> degree
  zero_f32<<<nbN, 256, 0, stream>>>((float*)rowst, N);
  count_slot<<<nbE, 256, 0, stream>>>(dstp, rowst, slot, E);
  const int nblk1 = (N + 255) / 256;  // <= 512 for N <= 131072
  scan_bsum<<<nblk1, 256, 0, stream>>>(rowst, bsum, N);
  scan_bscan<<<1, 512, 0, stream>>>(bsum, nblk1);
  scan_inplace<<<nblk1, 256, 0, stream>>>(rowst, bsum, N);
  fill_recs<<<nbE, 256, 0, stream>>>(src, dstp, ew, slot, rowst, recs, E);
  deg_rows<<<(N + 3) / 4, 256, 0, stream>>>(recs, rowst, dinv, N);

  // x -> bf16
  to_bf16_8<<<(N * 16 + 255) / 256, 256, 0, stream>>>(x, (unsigned short*)xb, N * 16);

  // layer 1 aggregate -> xa_b ; fused MLP ; layer 2 aggregate + sigmoid
  gather_l1<<<(N + 3) / 4, 256, 0, stream>>>(xb, recs, rowst, dinv, xab, N);
  fused_mlp<<<(N + 63) / 64, 256, 0, stream>>>(xab, W0, b0, W1, r2b, N);
  gather_l2<<<(N * 16 + 255) / 256, 256, 0, stream>>>(r2b, recs, rowst, dinv, b1, out, N);
}

// Round 6
// 524.973 us; speedup vs baseline: 15.6817x; 1.3611x over previous
//
#include <hip/hip_runtime.h>
#include <math.h>

// ---------------- bf16 helpers (RNE) ----------------

__device__ __forceinline__ unsigned short f2b(float f) {
  unsigned u = __float_as_uint(f);
  unsigned r = u + 0x7fffu + ((u >> 16) & 1u);
  return (unsigned short)(r >> 16);
}
__device__ __forceinline__ float b2f_lo(unsigned v) {
  return __uint_as_float(v << 16);
}
__device__ __forceinline__ float b2f_hi(unsigned v) {
  return __uint_as_float(v & 0xffff0000u);
}

// ---------------- small kernels ----------------

__global__ __launch_bounds__(256) void zero_f32(float* __restrict__ p, int n) {
  int i = blockIdx.x * 256 + threadIdx.x;
  if (i < n) p[i] = 0.f;
}

// one atomic per edge: in-row slot assignment + count histogram
__global__ __launch_bounds__(256) void count_slot(const int* __restrict__ dst,
                                                  int* __restrict__ count,
                                                  unsigned short* __restrict__ slot,
                                                  int E) {
  int i = blockIdx.x * 256 + threadIdx.x;
  if (i >= E) return;
  int p = atomicAdd(&count[dst[i]], 1);
  slot[i] = (unsigned short)p;  // max in-degree << 65536
}

// x (f32) -> xb (bf16), 8 elements/thread
__global__ __launch_bounds__(256) void to_bf16_8(const float* __restrict__ x,
                                                 unsigned short* __restrict__ xb,
                                                 int n8) {
  int i = blockIdx.x * 256 + threadIdx.x;
  if (i >= n8) return;
  const float4 a = *(const float4*)&x[(long)i * 8];
  const float4 b = *(const float4*)&x[(long)i * 8 + 4];
  uint4 o;
  o.x = (unsigned)f2b(a.x) | ((unsigned)f2b(a.y) << 16);
  o.y = (unsigned)f2b(a.z) | ((unsigned)f2b(a.w) << 16);
  o.z = (unsigned)f2b(b.x) | ((unsigned)f2b(b.y) << 16);
  o.w = (unsigned)f2b(b.z) | ((unsigned)f2b(b.w) << 16);
  *(uint4*)&xb[(long)i * 8] = o;
}

// ---------------- scan: count[N] -> exclusive row_start (in place) ----------------

__global__ __launch_bounds__(256) void scan_bsum(const int* __restrict__ count,
                                                 int* __restrict__ bsum, int N) {
  __shared__ int sm[256];
  int i = blockIdx.x * 256 + threadIdx.x;
  sm[threadIdx.x] = (i < N) ? count[i] : 0;
  __syncthreads();
  for (int off = 128; off > 0; off >>= 1) {
    if (threadIdx.x < off) sm[threadIdx.x] += sm[threadIdx.x + off];
    __syncthreads();
  }
  if (threadIdx.x == 0) bsum[blockIdx.x] = sm[0];
}

__global__ __launch_bounds__(512) void scan_bscan(int* __restrict__ bsum, int nblk) {
  __shared__ int sm[512];
  int t = threadIdx.x;
  int v = (t < nblk) ? bsum[t] : 0;
  sm[t] = v;
  __syncthreads();
  for (int off = 1; off < 512; off <<= 1) {
    int a = (t >= off) ? sm[t - off] : 0;
    __syncthreads();
    sm[t] += a;
    __syncthreads();
  }
  if (t < nblk) bsum[t] = sm[t] - v;  // exclusive
}

// in-place: cr[] holds count on entry, exclusive prefix (row_start) on exit; cr[N]=E.
__global__ __launch_bounds__(256) void scan_inplace(int* __restrict__ cr,
                                                    const int* __restrict__ bscan,
                                                    int N) {
  __shared__ int sm[256];
  int i = blockIdx.x * 256 + threadIdx.x;
  int t = threadIdx.x;
  int v = (i < N) ? cr[i] : 0;
  sm[t] = v;
  __syncthreads();
  for (int off = 1; off < 256; off <<= 1) {
    int a = (t >= off) ? sm[t - off] : 0;
    __syncthreads();
    sm[t] += a;
    __syncthreads();
  }
  int excl = sm[t] - v + bscan[blockIdx.x];
  if (i < N) cr[i] = excl;
  if (i == N - 1) cr[N] = excl + v;
}

// ---------------- atomic-free CSR fill: rec = (src<<15) | q15(ew) ----------------

__global__ __launch_bounds__(256) void fill_recs(const int* __restrict__ src,
                                                 const int* __restrict__ dst,
                                                 const float* __restrict__ ew,
                                                 const unsigned short* __restrict__ slot,
                                                 const int* __restrict__ row_start,
                                                 unsigned int* __restrict__ recs, int E) {
  int i = blockIdx.x * 256 + threadIdx.x;
  if (i >= E) return;
  int q = (int)(ew[i] * 32767.f + 0.5f);
  q = (q < 0) ? 0 : ((q > 32767) ? 32767 : q);
  int pos = row_start[dst[i]] + (int)slot[i];
  recs[pos] = ((unsigned int)src[i] << 15) | (unsigned int)q;
}

// ---------------- atomic-free degree: dinv[d] = rsqrt(2 + sum_row q/32767) ----------------

__global__ __launch_bounds__(256) void deg_rows(const unsigned int* __restrict__ recs,
                                                const int* __restrict__ row_start,
                                                float* __restrict__ dinv, int N) {
  const int lane = threadIdx.x & 63;
  const int d = blockIdx.x * 4 + (threadIdx.x >> 6);
  if (d >= N) return;
  const int beg = row_start[d], end = row_start[d + 1];
  float s = 0.f;
  for (int j = beg + lane; j < end; j += 64) s += (float)(recs[j] & 32767u);
  for (int off = 32; off > 0; off >>= 1) s += __shfl_down(s, off, 64);
  if (lane == 0) dinv[d] = rsqrtf(s * (1.f / 32767.f) + 2.0f);
}

// ---------------- fold dinv[src] into records: q' = q15( ew*dinv[src] / 0.75 ) ----------------
// ew*dinv[src] < 1*rsqrt(2) < 0.75. Removes the dependent dinv[s] load from both gathers.

__global__ __launch_bounds__(256) void fold_dinv(unsigned int* __restrict__ recs,
                                                 const float* __restrict__ dinv, int E) {
  int i = blockIdx.x * 256 + threadIdx.x;
  if (i >= E) return;
  const unsigned rec = recs[i];
  const int s = rec >> 15;
  const float v = (float)(rec & 32767u) * (1.f / 32767.f) * dinv[s];
  int q = (int)(v * (32767.f / 0.75f) + 0.5f);
  q = (q > 32767) ? 32767 : q;
  recs[i] = ((unsigned)s << 15) | (unsigned)q;
}

// ---------------- layer-1 gather (bf16 payload, 4x unrolled) ----------------
// one wave per dst node; lane covers 2 cols (uint); 4 row-loads in flight.

__global__ __launch_bounds__(256) void gather_l1(const unsigned int* __restrict__ xb,
                                                 const unsigned int* __restrict__ recs,
                                                 const int* __restrict__ row_start,
                                                 const float* __restrict__ dinv,
                                                 unsigned int* __restrict__ xab, int N) {
  const int lane = threadIdx.x & 63;
  const int d = blockIdx.x * 4 + (threadIdx.x >> 6);
  if (d >= N) return;
  const int beg = row_start[d], end = row_start[d + 1];
  const float dd = dinv[d];
  constexpr float S = 0.75f / 32767.f;
  const unsigned sv = xb[(long)d * 64 + lane];
  const float sl = 2.f * dd * dd;
  float a0 = b2f_lo(sv) * sl, a1 = b2f_hi(sv) * sl;
  float b0 = 0.f, b1v = 0.f;
  int j = beg;
  for (; j + 4 <= end; j += 4) {
    const unsigned r0 = recs[j], r1 = recs[j + 1], r2 = recs[j + 2], r3 = recs[j + 3];
    const unsigned v0 = xb[(long)(r0 >> 15) * 64 + lane];
    const unsigned v1 = xb[(long)(r1 >> 15) * 64 + lane];
    const unsigned v2 = xb[(long)(r2 >> 15) * 64 + lane];
    const unsigned v3 = xb[(long)(r3 >> 15) * 64 + lane];
    const float c0 = (float)(r0 & 32767u) * S * dd;
    const float c1 = (float)(r1 & 32767u) * S * dd;
    const float c2 = (float)(r2 & 32767u) * S * dd;
    const float c3 = (float)(r3 & 32767u) * S * dd;
    a0 = fmaf(c0, b2f_lo(v0), a0);
    a1 = fmaf(c0, b2f_hi(v0), a1);
    b0 = fmaf(c1, b2f_lo(v1), b0);
    b1v = fmaf(c1, b2f_hi(v1), b1v);
    a0 = fmaf(c2, b2f_lo(v2), a0);
    a1 = fmaf(c2, b2f_hi(v2), a1);
    b0 = fmaf(c3, b2f_lo(v3), b0);
    b1v = fmaf(c3, b2f_hi(v3), b1v);
  }
  for (; j < end; ++j) {
    const unsigned rec = recs[j];
    const unsigned v = xb[(long)(rec >> 15) * 64 + lane];
    const float cf = (float)(rec & 32767u) * S * dd;
    a0 = fmaf(cf, b2f_lo(v), a0);
    a1 = fmaf(cf, b2f_hi(v), a1);
  }
  a0 += b0;
  a1 += b1v;
  xab[(long)d * 64 + lane] = (unsigned)f2b(a0) | ((unsigned)f2b(a1) << 16);
}

// ---------------- fused MLP: r2b = bf16( relu(xa@W0 + b0) @ W1 ) ----------------

__global__ __launch_bounds__(256) void fused_mlp(const unsigned int* __restrict__ xab,
                                                 const float* __restrict__ W0,
                                                 const float* __restrict__ b0,
                                                 const float* __restrict__ W1,
                                                 unsigned int* __restrict__ r2b, int N) {
  __shared__ unsigned short Al[64][130];  // bf16 xa tile (pad -> conflict-free)
  __shared__ float Wl[128][32];           // W column slab
  __shared__ unsigned short Hl[64][130];  // bf16 h1 tile
  const int tid = threadIdx.x;
  const int row0 = blockIdx.x * 64;

  for (int i = tid; i < 64 * 64; i += 256) {
    const int r = i >> 6, cu = i & 63;
    unsigned v = 0;
    if (row0 + r < N) v = xab[(long)(row0 + r) * 64 + cu];
    *(unsigned*)&Al[r][cu * 2] = v;
  }

  const int r = tid >> 2;  // 64 rows
  const int q = tid & 3;   // 4 col-groups of 8
  for (int ph = 0; ph < 4; ++ph) {
    __syncthreads();
    for (int i = tid * 4; i < 128 * 32; i += 1024) {
      const int k = i >> 5, c = i & 31;
      *(float4*)&Wl[k][c] = *(const float4*)&W0[(long)k * 128 + ph * 32 + c];
    }
    __syncthreads();
    float acc[8] = {};
    for (int k = 0; k < 128; ++k) {
      const float av = __uint_as_float((unsigned)Al[r][k] << 16);
      const float4 w0 = *(const float4*)&Wl[k][q * 8];
      const float4 w1 = *(const float4*)&Wl[k][q * 8 + 4];
      acc[0] = fmaf(av, w0.x, acc[0]);
      acc[1] = fmaf(av, w0.y, acc[1]);
      acc[2] = fmaf(av, w0.z, acc[2]);
      acc[3] = fmaf(av, w0.w, acc[3]);
      acc[4] = fmaf(av, w1.x, acc[4]);
      acc[5] = fmaf(av, w1.y, acc[5]);
      acc[6] = fmaf(av, w1.z, acc[6]);
      acc[7] = fmaf(av, w1.w, acc[7]);
    }
    const int cbase = ph * 32 + q * 8;
#pragma unroll
    for (int c = 0; c < 8; c += 2) {
      const float h0 = fmaxf(acc[c] + b0[cbase + c], 0.f);
      const float h1v = fmaxf(acc[c + 1] + b0[cbase + c + 1], 0.f);
      *(unsigned*)&Hl[r][cbase + c] = (unsigned)f2b(h0) | ((unsigned)f2b(h1v) << 16);
    }
  }

  for (int ph = 0; ph < 2; ++ph) {
    __syncthreads();
    for (int i = tid * 4; i < 128 * 32; i += 1024) {
      const int k = i >> 5, c = i & 31;
      *(float4*)&Wl[k][c] = *(const float4*)&W1[(long)k * 64 + ph * 32 + c];
    }
    __syncthreads();
    float acc[8] = {};
    for (int k = 0; k < 128; ++k) {
      const float a = __uint_as_float((unsigned)Hl[r][k] << 16);
      const float4 w0 = *(const float4*)&Wl[k][q * 8];
      const float4 w1 = *(const float4*)&Wl[k][q * 8 + 4];
      acc[0] = fmaf(a, w0.x, acc[0]);
      acc[1] = fmaf(a, w0.y, acc[1]);
      acc[2] = fmaf(a, w0.z, acc[2]);
      acc[3] = fmaf(a, w0.w, acc[3]);
      acc[4] = fmaf(a, w1.x, acc[4]);
      acc[5] = fmaf(a, w1.y, acc[5]);
      acc[6] = fmaf(a, w1.z, acc[6]);
      acc[7] = fmaf(a, w1.w, acc[7]);
    }
    if (row0 + r < N) {
      uint2 o, o2;
      o.x = (unsigned)f2b(acc[0]) | ((unsigned)f2b(acc[1]) << 16);
      o.y = (unsigned)f2b(acc[2]) | ((unsigned)f2b(acc[3]) << 16);
      o2.x = (unsigned)f2b(acc[4]) | ((unsigned)f2b(acc[5]) << 16);
      o2.y = (unsigned)f2b(acc[6]) | ((unsigned)f2b(acc[7]) << 16);
      *(uint2*)&r2b[(long)(row0 + r) * 32 + ph * 16 + q * 4] = o;
      *(uint2*)&r2b[(long)(row0 + r) * 32 + ph * 16 + q * 4 + 2] = o2;
    }
  }
}

// ---------------- layer-2 gather + b1 + sigmoid (4x unrolled) ----------------
// 16 lanes per dst node; lane covers 4 cols via uint2 (4 bf16).

__global__ __launch_bounds__(256) void gather_l2(const unsigned int* __restrict__ r2b,
                                                 const unsigned int* __restrict__ recs,
                                                 const int* __restrict__ row_start,
                                                 const float* __restrict__ dinv,
                                                 const float* __restrict__ b1,
                                                 float* __restrict__ out, int N) {
  const int t = blockIdx.x * 256 + threadIdx.x;
  const int d = t >> 4;
  if (d >= N) return;
  const int jl = t & 15;
  const int beg = row_start[d], end = row_start[d + 1];
  const float dd = dinv[d];
  constexpr float S = 0.75f / 32767.f;
  const uint2 sv = *(const uint2*)&r2b[(long)d * 32 + jl * 2];
  const float sl = 2.f * dd * dd;
  float a0 = b2f_lo(sv.x) * sl, a1 = b2f_hi(sv.x) * sl;
  float a2 = b2f_lo(sv.y) * sl, a3 = b2f_hi(sv.y) * sl;
  float c0s = 0.f, c1s = 0.f, c2s = 0.f, c3s = 0.f;
  int j = beg;
  for (; j + 4 <= end; j += 4) {
    const unsigned r0 = recs[j], r1 = recs[j + 1], r2 = recs[j + 2], r3 = recs[j + 3];
    const uint2 v0 = *(const uint2*)&r2b[(long)(r0 >> 15) * 32 + jl * 2];
    const uint2 v1 = *(const uint2*)&r2b[(long)(r1 >> 15) * 32 + jl * 2];
    const uint2 v2 = *(const uint2*)&r2b[(long)(r2 >> 15) * 32 + jl * 2];
    const uint2 v3 = *(const uint2*)&r2b[(long)(r3 >> 15) * 32 + jl * 2];
    const float c0 = (float)(r0 & 32767u) * S * dd;
    const float c1 = (float)(r1 & 32767u) * S * dd;
    const float c2 = (float)(r2 & 32767u) * S * dd;
    const float c3 = (float)(r3 & 32767u) * S * dd;
    a0 = fmaf(c0, b2f_lo(v0.x), a0);
    a1 = fmaf(c0, b2f_hi(v0.x), a1);
    a2 = fmaf(c0, b2f_lo(v0.y), a2);
    a3 = fmaf(c0, b2f_hi(v0.y), a3);
    c0s = fmaf(c1, b2f_lo(v1.x), c0s);
    c1s = fmaf(c1, b2f_hi(v1.x), c1s);
    c2s = fmaf(c1, b2f_lo(v1.y), c2s);
    c3s = fmaf(c1, b2f_hi(v1.y), c3s);
    a0 = fmaf(c2, b2f_lo(v2.x), a0);
    a1 = fmaf(c2, b2f_hi(v2.x), a1);
    a2 = fmaf(c2, b2f_lo(v2.y), a2);
    a3 = fmaf(c2, b2f_hi(v2.y), a3);
    c0s = fmaf(c3, b2f_lo(v3.x), c0s);
    c1s = fmaf(c3, b2f_hi(v3.x), c1s);
    c2s = fmaf(c3, b2f_lo(v3.y), c2s);
    c3s = fmaf(c3, b2f_hi(v3.y), c3s);
  }
  for (; j < end; ++j) {
    const unsigned rec = recs[j];
    const uint2 v = *(const uint2*)&r2b[(long)(rec >> 15) * 32 + jl * 2];
    const float cf = (float)(rec & 32767u) * S * dd;
    a0 = fmaf(cf, b2f_lo(v.x), a0);
    a1 = fmaf(cf, b2f_hi(v.x), a1);
    a2 = fmaf(cf, b2f_lo(v.y), a2);
    a3 = fmaf(cf, b2f_hi(v.y), a3);
  }
  a0 += c0s; a1 += c1s; a2 += c2s; a3 += c3s;
  const int c = jl * 4;
  const float4 b = *(const float4*)&b1[c];
  float4 o;
  o.x = 1.f / (1.f + __expf(-(a0 + b.x)));
  o.y = 1.f / (1.f + __expf(-(a1 + b.y)));
  o.z = 1.f / (1.f + __expf(-(a2 + b.z)));
  o.w = 1.f / (1.f + __expf(-(a3 + b.w)));
  *(float4*)&out[(long)d * 64 + c] = o;
}

// ---------------- launch ----------------
// out = sigmoid( Ahat @ (relu((Ahat @ x) @ W0 + b0) @ W1) + b1 ),
// Ahat = D^-1/2 (A+2I) D^-1/2, using (Ahat x) W0 == Ahat (x W0).
// CSR built with ONE atomic per edge; dinv[src] folded into 15-bit record weights.
// Workspace ~71.2 MB (< 71.6 MB proven available in round 3).

extern "C" void kernel_launch(void* const* d_in, const int* in_sizes, int n_in,
                              void* d_out, int out_size, void* d_ws, size_t ws_size,
                              hipStream_t stream) {
  const float* x  = (const float*)d_in[0];
  const int* src  = (const int*)d_in[1];
  const float* ew = (const float*)d_in[2];
  const float* W0 = (const float*)d_in[3];
  const float* b0 = (const float*)d_in[4];
  const float* W1 = (const float*)d_in[5];
  const float* b1 = (const float*)d_in[6];
  float* out = (float*)d_out;

  const int N = in_sizes[0] / 128;
  const int E = in_sizes[2];
  const int* dstp = src + E;

  // layout (4B units): dinv[oN] | rowst[oN] | bsum[1024] | recs[E] | slot[E/2]
  //                  | xb[N*64] | xab[N*64]   (r2b reuses xb)
  float* ws = (float*)d_ws;
  const size_t oN = ((size_t)N + 255) & ~(size_t)255;
  float* dinv = ws;
  int* rowst = (int*)(ws + oN);
  int* bsum = rowst + oN;
  unsigned int* recs = (unsigned int*)(bsum + 1024);
  unsigned short* slot = (unsigned short*)(recs + E);
  unsigned int* xb = recs + E + ((size_t)E + 1) / 2;
  unsigned int* xab = xb + (size_t)N * 64;
  unsigned int* r2b = xb;  // xb dead after gather_l1

  const int nbN = (N + 255) / 256;
  const int nbE = (E + 255) / 256;

  // CSR build: count+slot (1 atomic/edge) -> scan -> fill -> degree -> fold dinv
  zero_f32<<<nbN, 256, 0, stream>>>((float*)rowst, N);
  count_slot<<<nbE, 256, 0, stream>>>(dstp, rowst, slot, E);
  const int nblk1 = (N + 255) / 256;  // <= 512 for N <= 131072
  scan_bsum<<<nblk1, 256, 0, stream>>>(rowst, bsum, N);
  scan_bscan<<<1, 512, 0, stream>>>(bsum, nblk1);
  scan_inplace<<<nblk1, 256, 0, stream>>>(rowst, bsum, N);
  fill_recs<<<nbE, 256, 0, stream>>>(src, dstp, ew, slot, rowst, recs, E);
  deg_rows<<<(N + 3) / 4, 256, 0, stream>>>(recs, rowst, dinv, N);
  fold_dinv<<<nbE, 256, 0, stream>>>(recs, dinv, E);

  // x -> bf16
  to_bf16_8<<<(N * 16 + 255) / 256, 256, 0, stream>>>(x, (unsigned short*)xb, N * 16);

  // layer 1 aggregate -> xa_b ; fused MLP ; layer 2 aggregate + sigmoid
  gather_l1<<<(N + 3) / 4, 256, 0, stream>>>(xb, recs, rowst, dinv, xab, N);
  fused_mlp<<<(N + 63) / 64, 256, 0, stream>>>(xab, W0, b0, W1, r2b, N);
  gather_l2<<<(N * 16 + 255) / 256, 256, 0, stream>>>(r2b, recs, rowst, dinv, b1, out, N);
}

// Round 7
// 421.390 us; speedup vs baseline: 19.5364x; 1.2458x over previous
//
#include <hip/hip_runtime.h>
#include <math.h>

typedef __attribute__((ext_vector_type(8))) short bf16x8;
typedef __attribute__((ext_vector_type(4))) float f32x4;

// ---------------- bf16 helpers (RNE) ----------------

__device__ __forceinline__ unsigned short f2b(float f) {
  unsigned u = __float_as_uint(f);
  unsigned r = u + 0x7fffu + ((u >> 16) & 1u);
  return (unsigned short)(r >> 16);
}
__device__ __forceinline__ float b2f_lo(unsigned v) {
  return __uint_as_float(v << 16);
}
__device__ __forceinline__ float b2f_hi(unsigned v) {
  return __uint_as_float(v & 0xffff0000u);
}

// ---------------- small kernels ----------------

__global__ __launch_bounds__(256) void zero_f32(float* __restrict__ p, int n) {
  int i = blockIdx.x * 256 + threadIdx.x;
  if (i < n) p[i] = 0.f;
}

// one atomic per edge: in-row slot assignment + count histogram
__global__ __launch_bounds__(256) void count_slot(const int* __restrict__ dst,
                                                  int* __restrict__ count,
                                                  unsigned short* __restrict__ slot,
                                                  int E) {
  int i = blockIdx.x * 256 + threadIdx.x;
  if (i >= E) return;
  int p = atomicAdd(&count[dst[i]], 1);
  slot[i] = (unsigned short)p;  // max in-degree << 65536
}

// x (f32) -> xb (bf16), 8 elements/thread
__global__ __launch_bounds__(256) void to_bf16_8(const float* __restrict__ x,
                                                 unsigned short* __restrict__ xb,
                                                 int n8) {
  int i = blockIdx.x * 256 + threadIdx.x;
  if (i >= n8) return;
  const float4 a = *(const float4*)&x[(long)i * 8];
  const float4 b = *(const float4*)&x[(long)i * 8 + 4];
  uint4 o;
  o.x = (unsigned)f2b(a.x) | ((unsigned)f2b(a.y) << 16);
  o.y = (unsigned)f2b(a.z) | ((unsigned)f2b(a.w) << 16);
  o.z = (unsigned)f2b(b.x) | ((unsigned)f2b(b.y) << 16);
  o.w = (unsigned)f2b(b.z) | ((unsigned)f2b(b.w) << 16);
  *(uint4*)&xb[(long)i * 8] = o;
}

// pack W (f32, row-major [K][C]) into per-lane MFMA B-fragments (bf16):
// frag[((ct*(K/32)+kk)*64 + lane)*8 + e] = bf16( W[kk*32 + (lane>>4)*8 + e][ct*16 + (lane&15)] )
__global__ __launch_bounds__(256) void pack_wfrag(const float* __restrict__ W,
                                                  unsigned short* __restrict__ frag,
                                                  int C, int total) {
  int i = blockIdx.x * 256 + threadIdx.x;
  if (i >= total) return;
  const int e = i & 7;
  const int lane = (i >> 3) & 63;
  const int t = i >> 9;       // ct*(K/32) + kk, K/32 == 4
  const int kk = t & 3;
  const int ct = t >> 2;
  const int k = kk * 32 + (lane >> 4) * 8 + e;
  const int c = ct * 16 + (lane & 15);
  frag[i] = f2b(W[(long)k * C + c]);
}

// ---------------- scan: count[N] -> exclusive row_start (in place) ----------------

__global__ __launch_bounds__(256) void scan_bsum(const int* __restrict__ count,
                                                 int* __restrict__ bsum, int N) {
  __shared__ int sm[256];
  int i = blockIdx.x * 256 + threadIdx.x;
  sm[threadIdx.x] = (i < N) ? count[i] : 0;
  __syncthreads();
  for (int off = 128; off > 0; off >>= 1) {
    if (threadIdx.x < off) sm[threadIdx.x] += sm[threadIdx.x + off];
    __syncthreads();
  }
  if (threadIdx.x == 0) bsum[blockIdx.x] = sm[0];
}

__global__ __launch_bounds__(512) void scan_bscan(int* __restrict__ bsum, int nblk) {
  __shared__ int sm[512];
  int t = threadIdx.x;
  int v = (t < nblk) ? bsum[t] : 0;
  sm[t] = v;
  __syncthreads();
  for (int off = 1; off < 512; off <<= 1) {
    int a = (t >= off) ? sm[t - off] : 0;
    __syncthreads();
    sm[t] += a;
    __syncthreads();
  }
  if (t < nblk) bsum[t] = sm[t] - v;  // exclusive
}

// in-place: cr[] holds count on entry, exclusive prefix (row_start) on exit; cr[N]=E.
__global__ __launch_bounds__(256) void scan_inplace(int* __restrict__ cr,
                                                    const int* __restrict__ bscan,
                                                    int N) {
  __shared__ int sm[256];
  int i = blockIdx.x * 256 + threadIdx.x;
  int t = threadIdx.x;
  int v = (i < N) ? cr[i] : 0;
  sm[t] = v;
  __syncthreads();
  for (int off = 1; off < 256; off <<= 1) {
    int a = (t >= off) ? sm[t - off] : 0;
    __syncthreads();
    sm[t] += a;
    __syncthreads();
  }
  int excl = sm[t] - v + bscan[blockIdx.x];
  if (i < N) cr[i] = excl;
  if (i == N - 1) cr[N] = excl + v;
}

// ---------------- atomic-free CSR fill: rec = (src<<15) | q15(ew) ----------------

__global__ __launch_bounds__(256) void fill_recs(const int* __restrict__ src,
                                                 const int* __restrict__ dst,
                                                 const float* __restrict__ ew,
                                                 const unsigned short* __restrict__ slot,
                                                 const int* __restrict__ row_start,
                                                 unsigned int* __restrict__ recs, int E) {
  int i = blockIdx.x * 256 + threadIdx.x;
  if (i >= E) return;
  int q = (int)(ew[i] * 32767.f + 0.5f);
  q = (q < 0) ? 0 : ((q > 32767) ? 32767 : q);
  int pos = row_start[dst[i]] + (int)slot[i];
  recs[pos] = ((unsigned int)src[i] << 15) | (unsigned int)q;
}

// ---------------- atomic-free degree: dinv[d] = rsqrt(2 + sum_row q/32767) ----------------

__global__ __launch_bounds__(256) void deg_rows(const unsigned int* __restrict__ recs,
                                                const int* __restrict__ row_start,
                                                float* __restrict__ dinv, int N) {
  const int lane = threadIdx.x & 63;
  const int d = blockIdx.x * 4 + (threadIdx.x >> 6);
  if (d >= N) return;
  const int beg = row_start[d], end = row_start[d + 1];
  float s = 0.f;
  for (int j = beg + lane; j < end; j += 64) s += (float)(recs[j] & 32767u);
  for (int off = 32; off > 0; off >>= 1) s += __shfl_down(s, off, 64);
  if (lane == 0) dinv[d] = rsqrtf(s * (1.f / 32767.f) + 2.0f);
}

// ---------------- fold dinv[src] into records: q' = q15( ew*dinv[src] / 0.75 ) ----------------

__global__ __launch_bounds__(256) void fold_dinv(unsigned int* __restrict__ recs,
                                                 const float* __restrict__ dinv, int E) {
  int i = blockIdx.x * 256 + threadIdx.x;
  if (i >= E) return;
  const unsigned rec = recs[i];
  const int s = rec >> 15;
  const float v = (float)(rec & 32767u) * (1.f / 32767.f) * dinv[s];
  int q = (int)(v * (32767.f / 0.75f) + 0.5f);
  q = (q > 32767) ? 32767 : q;
  recs[i] = ((unsigned)s << 15) | (unsigned)q;
}

// ---------------- layer-1 gather (bf16 payload, 8x unrolled) ----------------

__global__ __launch_bounds__(256) void gather_l1(const unsigned int* __restrict__ xb,
                                                 const unsigned int* __restrict__ recs,
                                                 const int* __restrict__ row_start,
                                                 const float* __restrict__ dinv,
                                                 unsigned int* __restrict__ xab, int N) {
  const int lane = threadIdx.x & 63;
  const int d = blockIdx.x * 4 + (threadIdx.x >> 6);
  if (d >= N) return;
  const int beg = row_start[d], end = row_start[d + 1];
  const float dd = dinv[d];
  constexpr float S = 0.75f / 32767.f;
  const unsigned sv = xb[(long)d * 64 + lane];
  const float sl = 2.f * dd * dd;
  float a0 = b2f_lo(sv) * sl, a1 = b2f_hi(sv) * sl;
  float b0 = 0.f, b1v = 0.f;
  int j = beg;
  for (; j + 8 <= end; j += 8) {
    const unsigned r0 = recs[j], r1 = recs[j + 1], r2 = recs[j + 2], r3 = recs[j + 3];
    const unsigned r4 = recs[j + 4], r5 = recs[j + 5], r6 = recs[j + 6], r7 = recs[j + 7];
    const unsigned v0 = xb[(long)(r0 >> 15) * 64 + lane];
    const unsigned v1 = xb[(long)(r1 >> 15) * 64 + lane];
    const unsigned v2 = xb[(long)(r2 >> 15) * 64 + lane];
    const unsigned v3 = xb[(long)(r3 >> 15) * 64 + lane];
    const unsigned v4 = xb[(long)(r4 >> 15) * 64 + lane];
    const unsigned v5 = xb[(long)(r5 >> 15) * 64 + lane];
    const unsigned v6 = xb[(long)(r6 >> 15) * 64 + lane];
    const unsigned v7 = xb[(long)(r7 >> 15) * 64 + lane];
    const float c0 = (float)(r0 & 32767u) * S * dd;
    const float c1 = (float)(r1 & 32767u) * S * dd;
    const float c2 = (float)(r2 & 32767u) * S * dd;
    const float c3 = (float)(r3 & 32767u) * S * dd;
    const float c4 = (float)(r4 & 32767u) * S * dd;
    const float c5 = (float)(r5 & 32767u) * S * dd;
    const float c6 = (float)(r6 & 32767u) * S * dd;
    const float c7 = (float)(r7 & 32767u) * S * dd;
    a0 = fmaf(c0, b2f_lo(v0), a0);
    a1 = fmaf(c0, b2f_hi(v0), a1);
    b0 = fmaf(c1, b2f_lo(v1), b0);
    b1v = fmaf(c1, b2f_hi(v1), b1v);
    a0 = fmaf(c2, b2f_lo(v2), a0);
    a1 = fmaf(c2, b2f_hi(v2), a1);
    b0 = fmaf(c3, b2f_lo(v3), b0);
    b1v = fmaf(c3, b2f_hi(v3), b1v);
    a0 = fmaf(c4, b2f_lo(v4), a0);
    a1 = fmaf(c4, b2f_hi(v4), a1);
    b0 = fmaf(c5, b2f_lo(v5), b0);
    b1v = fmaf(c5, b2f_hi(v5), b1v);
    a0 = fmaf(c6, b2f_lo(v6), a0);
    a1 = fmaf(c6, b2f_hi(v6), a1);
    b0 = fmaf(c7, b2f_lo(v7), b0);
    b1v = fmaf(c7, b2f_hi(v7), b1v);
  }
  for (; j < end; ++j) {
    const unsigned rec = recs[j];
    const unsigned v = xb[(long)(rec >> 15) * 64 + lane];
    const float cf = (float)(rec & 32767u) * S * dd;
    a0 = fmaf(cf, b2f_lo(v), a0);
    a1 = fmaf(cf, b2f_hi(v), a1);
  }
  a0 += b0;
  a1 += b1v;
  xab[(long)d * 64 + lane] = (unsigned)f2b(a0) | ((unsigned)f2b(a1) << 16);
}

// ---------------- fused MLP via MFMA: r2b = bf16( relu(xa@W0 + b0) @ W1 ) ----------------
// 4 waves/block, 16 rows/wave. A-frags straight from xab; B-frags prepacked.
// h1 lives in a per-WAVE LDS tile (no barriers). mfma_f32_16x16x32_bf16:
//   A: lane holds A[l&15][(l>>4)*8+e] ; B: lane holds B[(l>>4)*8+e][l&15]
//   C/D: lane,reg holds D[(l>>4)*4+reg][l&15]   (verified layout, learn_hip m89)

__global__ __launch_bounds__(256) void fused_mlp_mfma(
    const unsigned short* __restrict__ xab, const unsigned short* __restrict__ w0f,
    const float* __restrict__ b0, const unsigned short* __restrict__ w1f,
    unsigned short* __restrict__ r2b, int N) {
  __shared__ unsigned short Hl[4][16][136];  // per-wave h1 tile; stride 136 -> <=2-way banks
  const int tid = threadIdx.x;
  const int w = tid >> 6, l = tid & 63;
  const int lr = l & 15, lg = l >> 4;
  const int row0 = blockIdx.x * 64 + w * 16;

  // ---- A-fragments for the 4 k-tiles (clamped row for OOB lanes) ----
  int arow = row0 + lr;
  if (arow >= N) arow = N - 1;
  const unsigned short* ap = xab + (long)arow * 128 + lg * 8;
  const bf16x8 a0 = *(const bf16x8*)(ap);
  const bf16x8 a1 = *(const bf16x8*)(ap + 32);
  const bf16x8 a2 = *(const bf16x8*)(ap + 64);
  const bf16x8 a3 = *(const bf16x8*)(ap + 96);

  // ---- layer 1: h1[16][128] = relu(xa @ W0 + b0), 8 col-tiles ----
  for (int ct = 0; ct < 8; ++ct) {
    const unsigned short* bp = w0f + ct * 2048 + l * 8;
    f32x4 acc = {0.f, 0.f, 0.f, 0.f};
    acc = __builtin_amdgcn_mfma_f32_16x16x32_bf16(a0, *(const bf16x8*)(bp), acc, 0, 0, 0);
    acc = __builtin_amdgcn_mfma_f32_16x16x32_bf16(a1, *(const bf16x8*)(bp + 512), acc, 0, 0, 0);
    acc = __builtin_amdgcn_mfma_f32_16x16x32_bf16(a2, *(const bf16x8*)(bp + 1024), acc, 0, 0, 0);
    acc = __builtin_amdgcn_mfma_f32_16x16x32_bf16(a3, *(const bf16x8*)(bp + 1536), acc, 0, 0, 0);
    const float bv = b0[ct * 16 + lr];
#pragma unroll
    for (int r = 0; r < 4; ++r) {
      Hl[w][lg * 4 + r][ct * 16 + lr] = f2b(fmaxf(acc[r] + bv, 0.f));
    }
  }

  // ---- layer 2 A-fragments from the wave-private LDS tile ----
  const unsigned short* hp = &Hl[w][lr][lg * 8];
  const bf16x8 h0 = *(const bf16x8*)(hp);
  const bf16x8 h1 = *(const bf16x8*)(hp + 32);
  const bf16x8 h2 = *(const bf16x8*)(hp + 64);
  const bf16x8 h3 = *(const bf16x8*)(hp + 96);

  // ---- layer 2: r2[16][64] = h1 @ W1, 4 col-tiles ----
  for (int ct = 0; ct < 4; ++ct) {
    const unsigned short* bp = w1f + ct * 2048 + l * 8;
    f32x4 acc = {0.f, 0.f, 0.f, 0.f};
    acc = __builtin_amdgcn_mfma_f32_16x16x32_bf16(h0, *(const bf16x8*)(bp), acc, 0, 0, 0);
    acc = __builtin_amdgcn_mfma_f32_16x16x32_bf16(h1, *(const bf16x8*)(bp + 512), acc, 0, 0, 0);
    acc = __builtin_amdgcn_mfma_f32_16x16x32_bf16(h2, *(const bf16x8*)(bp + 1024), acc, 0, 0, 0);
    acc = __builtin_amdgcn_mfma_f32_16x16x32_bf16(h3, *(const bf16x8*)(bp + 1536), acc, 0, 0, 0);
#pragma unroll
    for (int r = 0; r < 4; ++r) {
      const int orow = row0 + lg * 4 + r;
      if (orow < N) r2b[(long)orow * 64 + ct * 16 + lr] = f2b(acc[r]);
    }
  }
}

// ---------------- layer-2 gather + b1 + sigmoid (8x unrolled) ----------------

__global__ __launch_bounds__(256) void gather_l2(const unsigned int* __restrict__ r2b,
                                                 const unsigned int* __restrict__ recs,
                                                 const int* __restrict__ row_start,
                                                 const float* __restrict__ dinv,
                                                 const float* __restrict__ b1,
                                                 float* __restrict__ out, int N) {
  const int t = blockIdx.x * 256 + threadIdx.x;
  const int d = t >> 4;
  if (d >= N) return;
  const int jl = t & 15;
  const int beg = row_start[d], end = row_start[d + 1];
  const float dd = dinv[d];
  constexpr float S = 0.75f / 32767.f;
  const uint2 sv = *(const uint2*)&r2b[(long)d * 32 + jl * 2];
  const float sl = 2.f * dd * dd;
  float a0 = b2f_lo(sv.x) * sl, a1 = b2f_hi(sv.x) * sl;
  float a2 = b2f_lo(sv.y) * sl, a3 = b2f_hi(sv.y) * sl;
  float c0s = 0.f, c1s = 0.f, c2s = 0.f, c3s = 0.f;
  int j = beg;
  for (; j + 8 <= end; j += 8) {
    const unsigned r0 = recs[j], r1 = recs[j + 1], r2 = recs[j + 2], r3 = recs[j + 3];
    const unsigned r4 = recs[j + 4], r5 = recs[j + 5], r6 = recs[j + 6], r7 = recs[j + 7];
    const uint2 v0 = *(const uint2*)&r2b[(long)(r0 >> 15) * 32 + jl * 2];
    const uint2 v1 = *(const uint2*)&r2b[(long)(r1 >> 15) * 32 + jl * 2];
    const uint2 v2 = *(const uint2*)&r2b[(long)(r2 >> 15) * 32 + jl * 2];
    const uint2 v3 = *(const uint2*)&r2b[(long)(r3 >> 15) * 32 + jl * 2];
    const uint2 v4 = *(const uint2*)&r2b[(long)(r4 >> 15) * 32 + jl * 2];
    const uint2 v5 = *(const uint2*)&r2b[(long)(r5 >> 15) * 32 + jl * 2];
    const uint2 v6 = *(const uint2*)&r2b[(long)(r6 >> 15) * 32 + jl * 2];
    const uint2 v7 = *(const uint2*)&r2b[(long)(r7 >> 15) * 32 + jl * 2];
    const float c0 = (float)(r0 & 32767u) * S * dd;
    const float c1 = (float)(r1 & 32767u) * S * dd;
    const float c2 = (float)(r2 & 32767u) * S * dd;
    const float c3 = (float)(r3 & 32767u) * S * dd;
    const float c4 = (float)(r4 & 32767u) * S * dd;
    const float c5 = (float)(r5 & 32767u) * S * dd;
    const float c6 = (float)(r6 & 32767u) * S * dd;
    const float c7 = (float)(r7 & 32767u) * S * dd;
    a0 = fmaf(c0, b2f_lo(v0.x), a0);
    a1 = fmaf(c0, b2f_hi(v0.x), a1);
    a2 = fmaf(c0, b2f_lo(v0.y), a2);
    a3 = fmaf(c0, b2f_hi(v0.y), a3);
    c0s = fmaf(c1, b2f_lo(v1.x), c0s);
    c1s = fmaf(c1, b2f_hi(v1.x), c1s);
    c2s = fmaf(c1, b2f_lo(v1.y), c2s);
    c3s = fmaf(c1, b2f_hi(v1.y), c3s);
    a0 = fmaf(c2, b2f_lo(v2.x), a0);
    a1 = fmaf(c2, b2f_hi(v2.x), a1);
    a2 = fmaf(c2, b2f_lo(v2.y), a2);
    a3 = fmaf(c2, b2f_hi(v2.y), a3);
    c0s = fmaf(c3, b2f_lo(v3.x), c0s);
    c1s = fmaf(c3, b2f_hi(v3.x), c1s);
    c2s = fmaf(c3, b2f_lo(v3.y), c2s);
    c3s = fmaf(c3, b2f_hi(v3.y), c3s);
    a0 = fmaf(c4, b2f_lo(v4.x), a0);
    a1 = fmaf(c4, b2f_hi(v4.x), a1);
    a2 = fmaf(c4, b2f_lo(v4.y), a2);
    a3 = fmaf(c4, b2f_hi(v4.y), a3);
    c0s = fmaf(c5, b2f_lo(v5.x), c0s);
    c1s = fmaf(c5, b2f_hi(v5.x), c1s);
    c2s = fmaf(c5, b2f_lo(v5.y), c2s);
    c3s = fmaf(c5, b2f_hi(v5.y), c3s);
    a0 = fmaf(c6, b2f_lo(v6.x), a0);
    a1 = fmaf(c6, b2f_hi(v6.x), a1);
    a2 = fmaf(c6, b2f_lo(v6.y), a2);
    a3 = fmaf(c6, b2f_hi(v6.y), a3);
    c0s = fmaf(c7, b2f_lo(v7.x), c0s);
    c1s = fmaf(c7, b2f_hi(v7.x), c1s);
    c2s = fmaf(c7, b2f_lo(v7.y), c2s);
    c3s = fmaf(c7, b2f_hi(v7.y), c3s);
  }
  for (; j < end; ++j) {
    const unsigned rec = recs[j];
    const uint2 v = *(const uint2*)&r2b[(long)(rec >> 15) * 32 + jl * 2];
    const float cf = (float)(rec & 32767u) * S * dd;
    a0 = fmaf(cf, b2f_lo(v.x), a0);
    a1 = fmaf(cf, b2f_hi(v.x), a1);
    a2 = fmaf(cf, b2f_lo(v.y), a2);
    a3 = fmaf(cf, b2f_hi(v.y), a3);
  }
  a0 += c0s; a1 += c1s; a2 += c2s; a3 += c3s;
  const int c = jl * 4;
  const float4 b = *(const float4*)&b1[c];
  float4 o;
  o.x = 1.f / (1.f + __expf(-(a0 + b.x)));
  o.y = 1.f / (1.f + __expf(-(a1 + b.y)));
  o.z = 1.f / (1.f + __expf(-(a2 + b.z)));
  o.w = 1.f / (1.f + __expf(-(a3 + b.w)));
  *(float4*)&out[(long)d * 64 + c] = o;
}

// ---------------- launch ----------------
// out = sigmoid( Ahat @ (relu((Ahat @ x) @ W0 + b0) @ W1) + b1 ),
// Ahat = D^-1/2 (A+2I) D^-1/2, using (Ahat x) W0 == Ahat (x W0).
// CSR: 1 atomic/edge; dinv folded into records; MLP on matrix cores (bf16 MFMA).
// Workspace ~71.25 MB (< 71.6 MB proven available in round 3).

extern "C" void kernel_launch(void* const* d_in, const int* in_sizes, int n_in,
                              void* d_out, int out_size, void* d_ws, size_t ws_size,
                              hipStream_t stream) {
  const float* x  = (const float*)d_in[0];
  const int* src  = (const int*)d_in[1];
  const float* ew = (const float*)d_in[2];
  const float* W0 = (const float*)d_in[3];
  const float* b0 = (const float*)d_in[4];
  const float* W1 = (const float*)d_in[5];
  const float* b1 = (const float*)d_in[6];
  float* out = (float*)d_out;

  const int N = in_sizes[0] / 128;
  const int E = in_sizes[2];
  const int* dstp = src + E;

  // layout (4B units): dinv[oN] | rowst[oN] | bsum[1024] | recs[E] | slot[E/2]
  //                  | xb[N*64] | xab[N*64] | w0f[8192] | w1f[4096]   (r2b reuses xb)
  float* ws = (float*)d_ws;
  const size_t oN = ((size_t)N + 255) & ~(size_t)255;
  float* dinv = ws;
  int* rowst = (int*)(ws + oN);
  int* bsum = rowst + oN;
  unsigned int* recs = (unsigned int*)(bsum + 1024);
  unsigned short* slot = (unsigned short*)(recs + E);
  unsigned int* xb = recs + E + ((size_t)E + 1) / 2;
  unsigned int* xab = xb + (size_t)N * 64;
  unsigned short* w0f = (unsigned short*)(xab + (size_t)N * 64);
  unsigned short* w1f = w0f + 16384;
  unsigned int* r2b = xb;  // xb dead after gather_l1

  const int nbN = (N + 255) / 256;
  const int nbE = (E + 255) / 256;

  // CSR build: count+slot (1 atomic/edge) -> scan -> fill -> degree -> fold dinv
  zero_f32<<<nbN, 256, 0, stream>>>((float*)rowst, N);
  count_slot<<<nbE, 256, 0, stream>>>(dstp, rowst, slot, E);
  const int nblk1 = (N + 255) / 256;  // <= 512 for N <= 131072
  scan_bsum<<<nblk1, 256, 0, stream>>>(rowst, bsum, N);
  scan_bscan<<<1, 512, 0, stream>>>(bsum, nblk1);
  scan_inplace<<<nblk1, 256, 0, stream>>>(rowst, bsum, N);
  fill_recs<<<nbE, 256, 0, stream>>>(src, dstp, ew, slot, rowst, recs, E);
  deg_rows<<<(N + 3) / 4, 256, 0, stream>>>(recs, rowst, dinv, N);
  fold_dinv<<<nbE, 256, 0, stream>>>(recs, dinv, E);

  // weight fragment prepack + x -> bf16
  pack_wfrag<<<64, 256, 0, stream>>>(W0, w0f, 128, 16384);
  pack_wfrag<<<32, 256, 0, stream>>>(W1, w1f, 64, 8192);
  to_bf16_8<<<(N * 16 + 255) / 256, 256, 0, stream>>>(x, (unsigned short*)xb, N * 16);

  // layer 1 aggregate -> xa_b ; fused MFMA MLP ; layer 2 aggregate + sigmoid
  gather_l1<<<(N + 3) / 4, 256, 0, stream>>>(xb, recs, rowst, dinv, xab, N);
  fused_mlp_mfma<<<(N + 63) / 64, 256, 0, stream>>>((const unsigned short*)xab, w0f, b0,
                                                    w1f, (unsigned short*)r2b, N);
  gather_l2<<<(N * 16 + 255) / 256, 256, 0, stream>>>(r2b, recs, rowst, dinv, b1, out, N);
}

// Round 8
// 326.293 us; speedup vs baseline: 25.2302x; 1.2914x over previous
//
#include <hip/hip_runtime.h>
#include <math.h>

typedef __attribute__((ext_vector_type(8))) short bf16x8;
typedef __attribute__((ext_vector_type(4))) float f32x4;

// ---------------- bf16 helpers (RNE) ----------------

__device__ __forceinline__ unsigned short f2b(float f) {
  unsigned u = __float_as_uint(f);
  unsigned r = u + 0x7fffu + ((u >> 16) & 1u);
  return (unsigned short)(r >> 16);
}
__device__ __forceinline__ float b2f_lo(unsigned v) {
  return __uint_as_float(v << 16);
}
__device__ __forceinline__ float b2f_hi(unsigned v) {
  return __uint_as_float(v & 0xffff0000u);
}

// ================= bucket-sort CSR build (no global atomics) =================
// bucket k covers dst in [k*64, k*64+64); all edges of a node share one bucket.

// per-block LDS histogram over NB buckets
__global__ __launch_bounds__(256) void bucket_hist(const int* __restrict__ dst,
                                                   int* __restrict__ blkhist,
                                                   int NB, int E, int chunk) {
  extern __shared__ int sm_hist[];
  for (int i = threadIdx.x; i < NB; i += 256) sm_hist[i] = 0;
  __syncthreads();
  const int b = blockIdx.x;
  const int beg = b * chunk;
  const int end = min(E, beg + chunk);
  for (int j = beg + threadIdx.x; j < end; j += 256)
    atomicAdd(&sm_hist[dst[j] >> 6], 1);
  __syncthreads();
  for (int i = threadIdx.x; i < NB; i += 256) blkhist[(long)b * NB + i] = sm_hist[i];
}

// column prefix over blocks: blkhist[b][k] -> prefix of earlier blocks; btot[k] = total
__global__ __launch_bounds__(256) void col_prefix(int* __restrict__ blkhist,
                                                  int* __restrict__ btot, int NB,
                                                  int nblk) {
  const int k = blockIdx.x * 256 + threadIdx.x;
  if (k >= NB) return;
  int run = 0;
  int b = 0;
  for (; b + 4 <= nblk; b += 4) {  // 4 loads in flight
    const int t0 = blkhist[(long)(b + 0) * NB + k];
    const int t1 = blkhist[(long)(b + 1) * NB + k];
    const int t2 = blkhist[(long)(b + 2) * NB + k];
    const int t3 = blkhist[(long)(b + 3) * NB + k];
    blkhist[(long)(b + 0) * NB + k] = run; run += t0;
    blkhist[(long)(b + 1) * NB + k] = run; run += t1;
    blkhist[(long)(b + 2) * NB + k] = run; run += t2;
    blkhist[(long)(b + 3) * NB + k] = run; run += t3;
  }
  for (; b < nblk; ++b) {
    const int t = blkhist[(long)b * NB + k];
    blkhist[(long)b * NB + k] = run;
    run += t;
  }
  btot[k] = run;
}

// ---------------- scan helpers (used for the NB-bucket scan) ----------------

__global__ __launch_bounds__(256) void scan_bsum(const int* __restrict__ count,
                                                 int* __restrict__ bsum, int N) {
  __shared__ int sm[256];
  int i = blockIdx.x * 256 + threadIdx.x;
  sm[threadIdx.x] = (i < N) ? count[i] : 0;
  __syncthreads();
  for (int off = 128; off > 0; off >>= 1) {
    if (threadIdx.x < off) sm[threadIdx.x] += sm[threadIdx.x + off];
    __syncthreads();
  }
  if (threadIdx.x == 0) bsum[blockIdx.x] = sm[0];
}

__global__ __launch_bounds__(512) void scan_bscan(int* __restrict__ bsum, int nblk) {
  __shared__ int sm[512];
  int t = threadIdx.x;
  int v = (t < nblk) ? bsum[t] : 0;
  sm[t] = v;
  __syncthreads();
  for (int off = 1; off < 512; off <<= 1) {
    int a = (t >= off) ? sm[t - off] : 0;
    __syncthreads();
    sm[t] += a;
    __syncthreads();
  }
  if (t < nblk) bsum[t] = sm[t] - v;  // exclusive
}

// in-place: cr[] holds counts on entry, exclusive prefix on exit; cr[N] = total.
__global__ __launch_bounds__(256) void scan_inplace(int* __restrict__ cr,
                                                    const int* __restrict__ bscan,
                                                    int N) {
  __shared__ int sm[256];
  int i = blockIdx.x * 256 + threadIdx.x;
  int t = threadIdx.x;
  int v = (i < N) ? cr[i] : 0;
  sm[t] = v;
  __syncthreads();
  for (int off = 1; off < 256; off <<= 1) {
    int a = (t >= off) ? sm[t - off] : 0;
    __syncthreads();
    sm[t] += a;
    __syncthreads();
  }
  int excl = sm[t] - v + bscan[blockIdx.x];
  if (i < N) cr[i] = excl;
  if (i == N - 1) cr[N] = excl + v;
}

// scatter edges into bucket ranges; positions via LDS cursors (no global atomics)
__global__ __launch_bounds__(256) void bucket_scatter(const int* __restrict__ src,
                                                      const int* __restrict__ dst,
                                                      const float* __restrict__ ew,
                                                      const int* __restrict__ blkhist,
                                                      const int* __restrict__ bstart,
                                                      uint2* __restrict__ bkt, int NB,
                                                      int E, int chunk) {
  extern __shared__ int sm_cur[];
  const int b = blockIdx.x;
  for (int i = threadIdx.x; i < NB; i += 256)
    sm_cur[i] = blkhist[(long)b * NB + i] + bstart[i];
  __syncthreads();
  const int beg = b * chunk;
  const int end = min(E, beg + chunk);
  for (int j = beg + threadIdx.x; j < end; j += 256) {
    const int d = dst[j];
    int q = (int)(ew[j] * 32767.f + 0.5f);
    q = (q < 0) ? 0 : ((q > 32767) ? 32767 : q);
    const unsigned rec = ((unsigned)src[j] << 15) | (unsigned)q;
    const int pos = atomicAdd(&sm_cur[d >> 6], 1);
    bkt[pos] = make_uint2(rec, (unsigned)(d & 63));
  }
}

// per-bucket: local 64-node CSR + row_start + deg/dinv, then scatter recs
__global__ __launch_bounds__(256) void bucket_finalize(const uint2* __restrict__ bkt,
                                                       const int* __restrict__ bstart,
                                                       unsigned* __restrict__ recs,
                                                       int* __restrict__ row_start,
                                                       float* __restrict__ dinv, int NB,
                                                       int N, int E) {
  __shared__ int hist[64], qs[64], cur[64], lstart[64];
  const int k = blockIdx.x;
  const int t = threadIdx.x;
  if (t < 64) { hist[t] = 0; qs[t] = 0; }
  __syncthreads();
  const int beg = bstart[k], end = bstart[k + 1];
  for (int j = beg + t; j < end; j += 256) {
    const uint2 v = bkt[j];
    atomicAdd(&hist[v.y], 1);
    atomicAdd(&qs[v.y], (int)(v.x & 32767u));
  }
  __syncthreads();
  if (t == 0) {
    int run = 0;
    for (int i = 0; i < 64; ++i) { lstart[i] = run; run += hist[i]; }
  }
  __syncthreads();
  if (t < 64) {
    cur[t] = lstart[t];
    const int node = k * 64 + t;
    if (node < N) {
      row_start[node] = beg + lstart[t];
      dinv[node] = rsqrtf((float)qs[t] * (1.f / 32767.f) + 2.0f);  // +2 self-loop
    }
  }
  if (k == NB - 1 && t == 0) row_start[N] = E;
  __syncthreads();
  for (int j = beg + t; j < end; j += 256) {
    const uint2 v = bkt[j];
    const int off = atomicAdd(&cur[v.y], 1);  // LDS atomic
    recs[beg + off] = v.x;
  }
}

// ---------------- fold dinv[src] into records: q' = q15( ew*dinv[src] / 0.75 ) ----------------

__global__ __launch_bounds__(256) void fold_dinv(unsigned int* __restrict__ recs,
                                                 const float* __restrict__ dinv, int E) {
  int i = blockIdx.x * 256 + threadIdx.x;
  if (i >= E) return;
  const unsigned rec = recs[i];
  const int s = rec >> 15;
  const float v = (float)(rec & 32767u) * (1.f / 32767.f) * dinv[s];
  int q = (int)(v * (32767.f / 0.75f) + 0.5f);
  q = (q > 32767) ? 32767 : q;
  recs[i] = ((unsigned)s << 15) | (unsigned)q;
}

// ---------------- x (f32) -> xb (bf16), 8 elements/thread ----------------

__global__ __launch_bounds__(256) void to_bf16_8(const float* __restrict__ x,
                                                 unsigned short* __restrict__ xb,
                                                 int n8) {
  int i = blockIdx.x * 256 + threadIdx.x;
  if (i >= n8) return;
  const float4 a = *(const float4*)&x[(long)i * 8];
  const float4 b = *(const float4*)&x[(long)i * 8 + 4];
  uint4 o;
  o.x = (unsigned)f2b(a.x) | ((unsigned)f2b(a.y) << 16);
  o.y = (unsigned)f2b(a.z) | ((unsigned)f2b(a.w) << 16);
  o.z = (unsigned)f2b(b.x) | ((unsigned)f2b(b.y) << 16);
  o.w = (unsigned)f2b(b.z) | ((unsigned)f2b(b.w) << 16);
  *(uint4*)&xb[(long)i * 8] = o;
}

// pack W (f32, row-major [K][C]) into per-lane MFMA B-fragments (bf16)
__global__ __launch_bounds__(256) void pack_wfrag(const float* __restrict__ W,
                                                  unsigned short* __restrict__ frag,
                                                  int C, int total) {
  int i = blockIdx.x * 256 + threadIdx.x;
  if (i >= total) return;
  const int e = i & 7;
  const int lane = (i >> 3) & 63;
  const int t = i >> 9;  // ct*(K/32) + kk, K/32 == 4
  const int kk = t & 3;
  const int ct = t >> 2;
  const int k = kk * 32 + (lane >> 4) * 8 + e;
  const int c = ct * 16 + (lane & 15);
  frag[i] = f2b(W[(long)k * C + c]);
}

// ---------------- layer-1 gather: 16 lanes/node, uint4 (16B) payloads, 8x unrolled ----------------

__global__ __launch_bounds__(256) void gather_l1(const uint4* __restrict__ xb4,
                                                 const unsigned int* __restrict__ recs,
                                                 const int* __restrict__ row_start,
                                                 const float* __restrict__ dinv,
                                                 uint4* __restrict__ xab4, int N) {
  const int t = blockIdx.x * 256 + threadIdx.x;
  const int d = t >> 4;
  if (d >= N) return;
  const int jl = t & 15;
  const int beg = row_start[d], end = row_start[d + 1];
  const float dd = dinv[d];
  constexpr float S = 0.75f / 32767.f;
  const uint4 sv = xb4[(long)d * 16 + jl];
  const float sl = 2.f * dd * dd;
  float aca[8], acb[8];
  aca[0] = b2f_lo(sv.x) * sl; aca[1] = b2f_hi(sv.x) * sl;
  aca[2] = b2f_lo(sv.y) * sl; aca[3] = b2f_hi(sv.y) * sl;
  aca[4] = b2f_lo(sv.z) * sl; aca[5] = b2f_hi(sv.z) * sl;
  aca[6] = b2f_lo(sv.w) * sl; aca[7] = b2f_hi(sv.w) * sl;
#pragma unroll
  for (int u = 0; u < 8; ++u) acb[u] = 0.f;
  int j = beg;
  for (; j + 8 <= end; j += 8) {
    unsigned rr[8];
    uint4 vv[8];
#pragma unroll
    for (int u = 0; u < 8; ++u) rr[u] = recs[j + u];
#pragma unroll
    for (int u = 0; u < 8; ++u) vv[u] = xb4[(long)(rr[u] >> 15) * 16 + jl];
#pragma unroll
    for (int u = 0; u < 8; ++u) {
      const float cf = (float)(rr[u] & 32767u) * S * dd;
      if (u & 1) {
        acb[0] = fmaf(cf, b2f_lo(vv[u].x), acb[0]);
        acb[1] = fmaf(cf, b2f_hi(vv[u].x), acb[1]);
        acb[2] = fmaf(cf, b2f_lo(vv[u].y), acb[2]);
        acb[3] = fmaf(cf, b2f_hi(vv[u].y), acb[3]);
        acb[4] = fmaf(cf, b2f_lo(vv[u].z), acb[4]);
        acb[5] = fmaf(cf, b2f_hi(vv[u].z), acb[5]);
        acb[6] = fmaf(cf, b2f_lo(vv[u].w), acb[6]);
        acb[7] = fmaf(cf, b2f_hi(vv[u].w), acb[7]);
      } else {
        aca[0] = fmaf(cf, b2f_lo(vv[u].x), aca[0]);
        aca[1] = fmaf(cf, b2f_hi(vv[u].x), aca[1]);
        aca[2] = fmaf(cf, b2f_lo(vv[u].y), aca[2]);
        aca[3] = fmaf(cf, b2f_hi(vv[u].y), aca[3]);
        aca[4] = fmaf(cf, b2f_lo(vv[u].z), aca[4]);
        aca[5] = fmaf(cf, b2f_hi(vv[u].z), aca[5]);
        aca[6] = fmaf(cf, b2f_lo(vv[u].w), aca[6]);
        aca[7] = fmaf(cf, b2f_hi(vv[u].w), aca[7]);
      }
    }
  }
  for (; j < end; ++j) {
    const unsigned rec = recs[j];
    const uint4 v = xb4[(long)(rec >> 15) * 16 + jl];
    const float cf = (float)(rec & 32767u) * S * dd;
    aca[0] = fmaf(cf, b2f_lo(v.x), aca[0]);
    aca[1] = fmaf(cf, b2f_hi(v.x), aca[1]);
    aca[2] = fmaf(cf, b2f_lo(v.y), aca[2]);
    aca[3] = fmaf(cf, b2f_hi(v.y), aca[3]);
    aca[4] = fmaf(cf, b2f_lo(v.z), aca[4]);
    aca[5] = fmaf(cf, b2f_hi(v.z), aca[5]);
    aca[6] = fmaf(cf, b2f_lo(v.w), aca[6]);
    aca[7] = fmaf(cf, b2f_hi(v.w), aca[7]);
  }
#pragma unroll
  for (int u = 0; u < 8; ++u) aca[u] += acb[u];
  uint4 o;
  o.x = (unsigned)f2b(aca[0]) | ((unsigned)f2b(aca[1]) << 16);
  o.y = (unsigned)f2b(aca[2]) | ((unsigned)f2b(aca[3]) << 16);
  o.z = (unsigned)f2b(aca[4]) | ((unsigned)f2b(aca[5]) << 16);
  o.w = (unsigned)f2b(aca[6]) | ((unsigned)f2b(aca[7]) << 16);
  xab4[(long)d * 16 + jl] = o;
}

// ---------------- fused MLP via MFMA (verified layout, unchanged) ----------------

__global__ __launch_bounds__(256) void fused_mlp_mfma(
    const unsigned short* __restrict__ xab, const unsigned short* __restrict__ w0f,
    const float* __restrict__ b0, const unsigned short* __restrict__ w1f,
    unsigned short* __restrict__ r2b, int N) {
  __shared__ unsigned short Hl[4][16][136];
  const int tid = threadIdx.x;
  const int w = tid >> 6, l = tid & 63;
  const int lr = l & 15, lg = l >> 4;
  const int row0 = blockIdx.x * 64 + w * 16;

  int arow = row0 + lr;
  if (arow >= N) arow = N - 1;
  const unsigned short* ap = xab + (long)arow * 128 + lg * 8;
  const bf16x8 a0 = *(const bf16x8*)(ap);
  const bf16x8 a1 = *(const bf16x8*)(ap + 32);
  const bf16x8 a2 = *(const bf16x8*)(ap + 64);
  const bf16x8 a3 = *(const bf16x8*)(ap + 96);

  for (int ct = 0; ct < 8; ++ct) {
    const unsigned short* bp = w0f + ct * 2048 + l * 8;
    f32x4 acc = {0.f, 0.f, 0.f, 0.f};
    acc = __builtin_amdgcn_mfma_f32_16x16x32_bf16(a0, *(const bf16x8*)(bp), acc, 0, 0, 0);
    acc = __builtin_amdgcn_mfma_f32_16x16x32_bf16(a1, *(const bf16x8*)(bp + 512), acc, 0, 0, 0);
    acc = __builtin_amdgcn_mfma_f32_16x16x32_bf16(a2, *(const bf16x8*)(bp + 1024), acc, 0, 0, 0);
    acc = __builtin_amdgcn_mfma_f32_16x16x32_bf16(a3, *(const bf16x8*)(bp + 1536), acc, 0, 0, 0);
    const float bv = b0[ct * 16 + lr];
#pragma unroll
    for (int r = 0; r < 4; ++r) {
      Hl[w][lg * 4 + r][ct * 16 + lr] = f2b(fmaxf(acc[r] + bv, 0.f));
    }
  }

  const unsigned short* hp = &Hl[w][lr][lg * 8];
  const bf16x8 h0 = *(const bf16x8*)(hp);
  const bf16x8 h1 = *(const bf16x8*)(hp + 32);
  const bf16x8 h2 = *(const bf16x8*)(hp + 64);
  const bf16x8 h3 = *(const bf16x8*)(hp + 96);

  for (int ct = 0; ct < 4; ++ct) {
    const unsigned short* bp = w1f + ct * 2048 + l * 8;
    f32x4 acc = {0.f, 0.f, 0.f, 0.f};
    acc = __builtin_amdgcn_mfma_f32_16x16x32_bf16(h0, *(const bf16x8*)(bp), acc, 0, 0, 0);
    acc = __builtin_amdgcn_mfma_f32_16x16x32_bf16(h1, *(const bf16x8*)(bp + 512), acc, 0, 0, 0);
    acc = __builtin_amdgcn_mfma_f32_16x16x32_bf16(h2, *(const bf16x8*)(bp + 1024), acc, 0, 0, 0);
    acc = __builtin_amdgcn_mfma_f32_16x16x32_bf16(h3, *(const bf16x8*)(bp + 1536), acc, 0, 0, 0);
#pragma unroll
    for (int r = 0; r < 4; ++r) {
      const int orow = row0 + lg * 4 + r;
      if (orow < N) r2b[(long)orow * 64 + ct * 16 + lr] = f2b(acc[r]);
    }
  }
}

// ---------------- layer-2 gather + b1 + sigmoid: 8 lanes/node, uint4, 8x unrolled ----------------

__global__ __launch_bounds__(256) void gather_l2(const uint4* __restrict__ r2b4,
                                                 const unsigned int* __restrict__ recs,
                                                 const int* __restrict__ row_start,
                                                 const float* __restrict__ dinv,
                                                 const float* __restrict__ b1,
                                                 float* __restrict__ out, int N) {
  const int t = blockIdx.x * 256 + threadIdx.x;
  const int d = t >> 3;
  if (d >= N) return;
  const int jl = t & 7;
  const int beg = row_start[d], end = row_start[d + 1];
  const float dd = dinv[d];
  constexpr float S = 0.75f / 32767.f;
  const uint4 sv = r2b4[(long)d * 8 + jl];
  const float sl = 2.f * dd * dd;
  float aca[8], acb[8];
  aca[0] = b2f_lo(sv.x) * sl; aca[1] = b2f_hi(sv.x) * sl;
  aca[2] = b2f_lo(sv.y) * sl; aca[3] = b2f_hi(sv.y) * sl;
  aca[4] = b2f_lo(sv.z) * sl; aca[5] = b2f_hi(sv.z) * sl;
  aca[6] = b2f_lo(sv.w) * sl; aca[7] = b2f_hi(sv.w) * sl;
#pragma unroll
  for (int u = 0; u < 8; ++u) acb[u] = 0.f;
  int j = beg;
  for (; j + 8 <= end; j += 8) {
    unsigned rr[8];
    uint4 vv[8];
#pragma unroll
    for (int u = 0; u < 8; ++u) rr[u] = recs[j + u];
#pragma unroll
    for (int u = 0; u < 8; ++u) vv[u] = r2b4[(long)(rr[u] >> 15) * 8 + jl];
#pragma unroll
    for (int u = 0; u < 8; ++u) {
      const float cf = (float)(rr[u] & 32767u) * S * dd;
      if (u & 1) {
        acb[0] = fmaf(cf, b2f_lo(vv[u].x), acb[0]);
        acb[1] = fmaf(cf, b2f_hi(vv[u].x), acb[1]);
        acb[2] = fmaf(cf, b2f_lo(vv[u].y), acb[2]);
        acb[3] = fmaf(cf, b2f_hi(vv[u].y), acb[3]);
        acb[4] = fmaf(cf, b2f_lo(vv[u].z), acb[4]);
        acb[5] = fmaf(cf, b2f_hi(vv[u].z), acb[5]);
        acb[6] = fmaf(cf, b2f_lo(vv[u].w), acb[6]);
        acb[7] = fmaf(cf, b2f_hi(vv[u].w), acb[7]);
      } else {
        aca[0] = fmaf(cf, b2f_lo(vv[u].x), aca[0]);
        aca[1] = fmaf(cf, b2f_hi(vv[u].x), aca[1]);
        aca[2] = fmaf(cf, b2f_lo(vv[u].y), aca[2]);
        aca[3] = fmaf(cf, b2f_hi(vv[u].y), aca[3]);
        aca[4] = fmaf(cf, b2f_lo(vv[u].z), aca[4]);
        aca[5] = fmaf(cf, b2f_hi(vv[u].z), aca[5]);
        aca[6] = fmaf(cf, b2f_lo(vv[u].w), aca[6]);
        aca[7] = fmaf(cf, b2f_hi(vv[u].w), aca[7]);
      }
    }
  }
  for (; j < end; ++j) {
    const unsigned rec = recs[j];
    const uint4 v = r2b4[(long)(rec >> 15) * 8 + jl];
    const float cf = (float)(rec & 32767u) * S * dd;
    aca[0] = fmaf(cf, b2f_lo(v.x), aca[0]);
    aca[1] = fmaf(cf, b2f_hi(v.x), aca[1]);
    aca[2] = fmaf(cf, b2f_lo(v.y), aca[2]);
    aca[3] = fmaf(cf, b2f_hi(v.y), aca[3]);
    aca[4] = fmaf(cf, b2f_lo(v.z), aca[4]);
    aca[5] = fmaf(cf, b2f_hi(v.z), aca[5]);
    aca[6] = fmaf(cf, b2f_lo(v.w), aca[6]);
    aca[7] = fmaf(cf, b2f_hi(v.w), aca[7]);
  }
#pragma unroll
  for (int u = 0; u < 8; ++u) aca[u] += acb[u];
  const int c = jl * 8;
  const float4 ba = *(const float4*)&b1[c];
  const float4 bb = *(const float4*)&b1[c + 4];
  float4 o1, o2;
  o1.x = 1.f / (1.f + __expf(-(aca[0] + ba.x)));
  o1.y = 1.f / (1.f + __expf(-(aca[1] + ba.y)));
  o1.z = 1.f / (1.f + __expf(-(aca[2] + ba.z)));
  o1.w = 1.f / (1.f + __expf(-(aca[3] + ba.w)));
  o2.x = 1.f / (1.f + __expf(-(aca[4] + bb.x)));
  o2.y = 1.f / (1.f + __expf(-(aca[5] + bb.y)));
  o2.z = 1.f / (1.f + __expf(-(aca[6] + bb.z)));
  o2.w = 1.f / (1.f + __expf(-(aca[7] + bb.w)));
  *(float4*)&out[(long)d * 64 + c] = o1;
  *(float4*)&out[(long)d * 64 + c + 4] = o2;
}

// ---------------- launch ----------------
// out = sigmoid( Ahat @ (relu((Ahat @ x) @ W0 + b0) @ W1) + b1 ),
// Ahat = D^-1/2 (A+2I) D^-1/2, using (Ahat x) W0 == Ahat (x W0).
// CSR via LDS-histogram bucket sort (ZERO global atomics); MLP on matrix cores.
// Workspace ~66.5 MB (< 71.6 MB proven available).

extern "C" void kernel_launch(void* const* d_in, const int* in_sizes, int n_in,
                              void* d_out, int out_size, void* d_ws, size_t ws_size,
                              hipStream_t stream) {
  const float* x  = (const float*)d_in[0];
  const int* src  = (const int*)d_in[1];
  const float* ew = (const float*)d_in[2];
  const float* W0 = (const float*)d_in[3];
  const float* b0 = (const float*)d_in[4];
  const float* W1 = (const float*)d_in[5];
  const float* b1 = (const float*)d_in[6];
  float* out = (float*)d_out;

  const int N = in_sizes[0] / 128;
  const int E = in_sizes[2];
  const int* dstp = src + E;

  const int NB = (N + 63) >> 6;        // buckets of 64 nodes
  const int NBLK = 256;                // histogram/scatter blocks
  const int chunk = (E + NBLK - 1) / NBLK;

  // layout (4B units): dinv[oN] | rowst[oN] | bstart[2048] | bsum[1024]
  //   | blkhist[NBLK*NB] | recs[E] | xb/bkt[max(2E, N*64)] | xab[N*64] | w0f | w1f
  float* ws = (float*)d_ws;
  const size_t oN = ((size_t)N + 255) & ~(size_t)255;
  float* dinv = ws;
  int* rowst = (int*)(ws + oN);
  int* bstart = rowst + oN;
  int* bsum = bstart + 2048;
  int* blkhist = bsum + 1024;
  unsigned int* recs = (unsigned int*)(blkhist + (size_t)NBLK * NB);
  unsigned int* xb = recs + E;               // aliases bkt
  uint2* bkt = (uint2*)xb;
  const size_t xb_units = ((size_t)2 * E > (size_t)N * 64) ? (size_t)2 * E : (size_t)N * 64;
  unsigned int* xab = xb + xb_units;
  unsigned short* w0f = (unsigned short*)(xab + (size_t)N * 64);
  unsigned short* w1f = w0f + 16384;
  unsigned int* r2b = xb;  // xb dead after gather_l1

  const int nbE = (E + 255) / 256;
  const int nblkB = (NB + 255) / 256;  // blocks for NB-wide kernels (<= 512 assumed)

  // ---- CSR build via bucket sort (no global atomics) ----
  bucket_hist<<<NBLK, 256, NB * 4, stream>>>(dstp, blkhist, NB, E, chunk);
  col_prefix<<<nblkB, 256, 0, stream>>>(blkhist, bstart, NB, NBLK);
  scan_bsum<<<nblkB, 256, 0, stream>>>(bstart, bsum, NB);
  scan_bscan<<<1, 512, 0, stream>>>(bsum, nblkB);
  scan_inplace<<<nblkB, 256, 0, stream>>>(bstart, bsum, NB);
  bucket_scatter<<<NBLK, 256, NB * 4, stream>>>(src, dstp, ew, blkhist, bstart, bkt, NB,
                                                E, chunk);
  bucket_finalize<<<NB, 256, 0, stream>>>(bkt, bstart, recs, rowst, dinv, NB, N, E);
  fold_dinv<<<nbE, 256, 0, stream>>>(recs, dinv, E);

  // ---- weights + features to bf16 ----
  pack_wfrag<<<64, 256, 0, stream>>>(W0, w0f, 128, 16384);
  pack_wfrag<<<32, 256, 0, stream>>>(W1, w1f, 64, 8192);
  to_bf16_8<<<(N * 16 + 255) / 256, 256, 0, stream>>>(x, (unsigned short*)xb, N * 16);

  // ---- layer 1 aggregate ; fused MFMA MLP ; layer 2 aggregate + sigmoid ----
  gather_l1<<<(N * 16 + 255) / 256, 256, 0, stream>>>((const uint4*)xb, recs, rowst, dinv,
                                                      (uint4*)xab, N);
  fused_mlp_mfma<<<(N + 63) / 64, 256, 0, stream>>>((const unsigned short*)xab, w0f, b0,
                                                    w1f, (unsigned short*)r2b, N);
  gather_l2<<<(N * 8 + 255) / 256, 256, 0, stream>>>((const uint4*)r2b, recs, rowst, dinv,
                                                     b1, out, N);
}